// Round 4
// baseline (1709.128 us; speedup 1.0000x reference)
//
#include <hip/hip_runtime.h>

// GCNe: 3-layer edge-weighted GCN + mean pool + linear head.
// N=100000, E=1000000, F=H=64, G=256, C=10.
//
// R4: bucket edges by dst>>6 (no exact sort -> no write amplification), then
// one fused kernel per layer: block = 64-node bucket; LDS f32 agg via
// ds_add_f32 edge-parallel gather, then MFMA GEMM relu(agg@Wr + x@Ws + b)
// straight out of LDS. bf16 storage for all node features.

#define GCN_F 64
#define GCN_C 10
#define NB 64            // nodes per bucket

typedef __attribute__((ext_vector_type(8))) short bf16x8;
typedef __attribute__((ext_vector_type(4))) float f32x4;

__device__ __forceinline__ unsigned short f2b(float v) {
    union { float f; unsigned int u; } c; c.f = v;
    unsigned int u = c.u;
    return (unsigned short)((u + 0x7FFFu + ((u >> 16) & 1u)) >> 16);  // RNE
}
__device__ __forceinline__ float b2f(unsigned short u) {
    union { unsigned int u; float f; } c; c.u = ((unsigned int)u) << 16; return c.f;
}

// ------------------------------------------------------- bucket histogram
__global__ __launch_bounds__(256) void bhist_kernel(const int* __restrict__ dst,
                                                    int* __restrict__ bcnt, int E) {
    int e = blockIdx.x * blockDim.x + threadIdx.x;
    if (e < E) atomicAdd(&bcnt[dst[e] >> 6], 1);
}

// ------------------------------------------------- bucket scan (one wave)
__global__ void bscan_kernel(const int* __restrict__ bcnt, int* __restrict__ bstart,
                             int nb) {
    int lane = threadIdx.x;
    int carry = 0;
    for (int base = 0; base < nb; base += 64) {
        int i = base + lane;
        int v = (i < nb) ? bcnt[i] : 0;
        int sc = v;
#pragma unroll
        for (int off = 1; off < 64; off <<= 1) {
            int t = __shfl_up(sc, off);
            if (lane >= off) sc += t;
        }
        if (i < nb) bstart[i] = carry + sc - v;   // exclusive
        carry += __shfl(sc, 63);
    }
    if (lane == 0) bstart[nb] = carry;            // = E
}

// -------------------------------------------------- scatter into buckets
// packed.x = src | (dst&63)<<26 ; packed.y = bits(ew)
__global__ __launch_bounds__(256) void scatterA_kernel(
    const int* __restrict__ src, const int* __restrict__ dst,
    const float* __restrict__ ew, const int* __restrict__ bstart,
    int* __restrict__ bcursor, int2* __restrict__ ebuf, int E) {
    int e = blockIdx.x * blockDim.x + threadIdx.x;
    if (e < E) {
        int d = dst[e];
        int b = d >> 6;
        int pos = bstart[b] + atomicAdd(&bcursor[b], 1);
        int2 rec;
        rec.x = src[e] | ((d & 63) << 26);
        rec.y = __float_as_int(ew[e]);
        ebuf[pos] = rec;
    }
}

// ----------------------------------------------------- fp32 -> bf16 convert
__global__ __launch_bounds__(256) void cvt_kernel(const float* __restrict__ in,
                                                  unsigned short* __restrict__ out,
                                                  int n4) {
    int stride = gridDim.x * blockDim.x;
    for (int i = blockIdx.x * blockDim.x + threadIdx.x; i < n4; i += stride) {
        float4 v = reinterpret_cast<const float4*>(in)[i];
        ushort4 o;
        o.x = f2b(v.x); o.y = f2b(v.y); o.z = f2b(v.z); o.w = f2b(v.w);
        reinterpret_cast<ushort4*>(out)[i] = o;
    }
}

// ---------------- fused layer: agg = A.x (LDS), h = relu(agg@Wr + x@Ws + b)
// One block per 64-node bucket. Phase 2: edge-parallel gather + ds_add_f32.
// Phase 3: MFMA 16x16x32 bf16; A row=l&15,k=(l>>4)*8+j; C col=l&15,row=(l>>4)*4+r.
__global__ __launch_bounds__(256) void layer_fused(
    const unsigned short* __restrict__ xin, const int* __restrict__ bstart,
    const int2* __restrict__ ebuf, const float* __restrict__ Wr,
    const float* __restrict__ Ws, const float* __restrict__ b,
    unsigned short* __restrict__ out, int n)
{
    __shared__ float agg[NB][GCN_F + 1];                          // 16.6 KB (+1: banks)
    __shared__ __align__(16) unsigned short bfrag[2][2][4][64][8]; // 16 KB
    int tid = threadIdx.x, lane = tid & 63, wave = tid >> 6;
    int bkt = blockIdx.x;

    // zero agg
    for (int i = tid; i < NB * (GCN_F + 1); i += 256) ((float*)agg)[i] = 0.f;
    // build B fragments: [op][ks][ct][lane][j]
    for (int i = tid; i < 8192; i += 256) {
        int op = i >> 12;
        int ks = (i >> 11) & 1;
        int ct = (i >> 9) & 3;
        int l  = (i >> 3) & 63;
        int j  = i & 7;
        int k   = ks * 32 + (l >> 4) * 8 + j;
        int col = ct * 16 + (l & 15);
        const float* W = op ? Ws : Wr;
        ((unsigned short*)bfrag)[i] = f2b(W[k * GCN_F + col]);
    }
    __syncthreads();

    // ---- phase 2: edge gather + LDS atomic accumulate
    int e0 = bstart[bkt], e1 = bstart[bkt + 1];
    int cnt = e1 - e0;
    int per = (cnt + 3) >> 2;
    int q0 = e0 + wave * per;
    int q1 = min(q0 + per, e1);
    int i = q0;
    for (; i + 4 <= q1; i += 4) {
        int2 eA = ebuf[i + 0];
        int2 eB = ebuf[i + 1];
        int2 eC = ebuf[i + 2];
        int2 eD = ebuf[i + 3];
        int sA = eA.x & 0x3FFFFFF, dA = (unsigned)eA.x >> 26;
        int sB = eB.x & 0x3FFFFFF, dB = (unsigned)eB.x >> 26;
        int sC = eC.x & 0x3FFFFFF, dC = (unsigned)eC.x >> 26;
        int sD = eD.x & 0x3FFFFFF, dD = (unsigned)eD.x >> 26;
        float rA = b2f(xin[(size_t)sA * GCN_F + lane]);
        float rB = b2f(xin[(size_t)sB * GCN_F + lane]);
        float rC = b2f(xin[(size_t)sC * GCN_F + lane]);
        float rD = b2f(xin[(size_t)sD * GCN_F + lane]);
        unsafeAtomicAdd(&agg[dA][lane], rA * __int_as_float(eA.y));
        unsafeAtomicAdd(&agg[dB][lane], rB * __int_as_float(eB.y));
        unsafeAtomicAdd(&agg[dC][lane], rC * __int_as_float(eC.y));
        unsafeAtomicAdd(&agg[dD][lane], rD * __int_as_float(eD.y));
    }
    for (; i < q1; ++i) {
        int2 eA = ebuf[i];
        int sA = eA.x & 0x3FFFFFF, dA = (unsigned)eA.x >> 26;
        float rA = b2f(xin[(size_t)sA * GCN_F + lane]);
        unsafeAtomicAdd(&agg[dA][lane], rA * __int_as_float(eA.y));
    }
    __syncthreads();

    // ---- phase 3: MFMA GEMM for this bucket's 64 rows; wave -> 16-row tile
    int l15 = lane & 15, lhi = lane >> 4;

    bf16x8 B[2][2][4];
#pragma unroll
    for (int op = 0; op < 2; ++op)
#pragma unroll
        for (int ks = 0; ks < 2; ++ks)
#pragma unroll
            for (int ct = 0; ct < 4; ++ct)
                B[op][ks][ct] = *reinterpret_cast<const bf16x8*>(&bfrag[op][ks][ct][lane][0]);

    float bias[4];
#pragma unroll
    for (int ct = 0; ct < 4; ++ct) bias[ct] = b[ct * 16 + l15];

    int lrow = wave * 16 + l15;                  // row within bucket
    int grow = bkt * NB + lrow;                  // global row (A operand)
    // aggregate A fragments from LDS (f32 -> bf16)
    bf16x8 a0, a1;
#pragma unroll
    for (int j = 0; j < 8; ++j) {
        a0[j] = (short)f2b(agg[lrow][0  + lhi * 8 + j]);
        a1[j] = (short)f2b(agg[lrow][32 + lhi * 8 + j]);
    }
    // root A fragments from global
    const unsigned short* xp = xin + (size_t)min(grow, n - 1) * GCN_F + lhi * 8;
    bf16x8 x0 = *reinterpret_cast<const bf16x8*>(xp);
    bf16x8 x1 = *reinterpret_cast<const bf16x8*>(xp + 32);

#pragma unroll
    for (int ct = 0; ct < 4; ++ct) {
        f32x4 acc = {0.f, 0.f, 0.f, 0.f};
        acc = __builtin_amdgcn_mfma_f32_16x16x32_bf16(a0, B[0][0][ct], acc, 0, 0, 0);
        acc = __builtin_amdgcn_mfma_f32_16x16x32_bf16(a1, B[0][1][ct], acc, 0, 0, 0);
        acc = __builtin_amdgcn_mfma_f32_16x16x32_bf16(x0, B[1][0][ct], acc, 0, 0, 0);
        acc = __builtin_amdgcn_mfma_f32_16x16x32_bf16(x1, B[1][1][ct], acc, 0, 0, 0);
        int col = ct * 16 + l15;
#pragma unroll
        for (int r = 0; r < 4; ++r) {
            int orow = bkt * NB + wave * 16 + lhi * 4 + r;
            if (orow < n) {
                float v = fmaxf(acc[r] + bias[ct], 0.f);
                out[(size_t)orow * GCN_F + col] = f2b(v);
            }
        }
    }
}

// ------------------------------------------------- mean pool + linear head
__global__ __launch_bounds__(256) void pool_kernel(
    const unsigned short* __restrict__ h, const int* __restrict__ batch,
    const float* __restrict__ Wl, const float* __restrict__ bl,
    float* __restrict__ out, int n)
{
    int g    = blockIdx.x;
    int tid  = threadIdx.x;
    int lane = tid & 63;
    int wave = tid >> 6;

    int i0, i1;
    {
        int lo = 0, hi = n;
        while (lo < hi) { int mid = (lo + hi) >> 1; if (batch[mid] < g) lo = mid + 1; else hi = mid; }
        i0 = lo;
        lo = i0; hi = n;
        while (lo < hi) { int mid = (lo + hi) >> 1; if (batch[mid] < g + 1) lo = mid + 1; else hi = mid; }
        i1 = lo;
    }

    float s = 0.f;
    for (int i = i0 + wave; i < i1; i += 4) s += b2f(h[(size_t)i * GCN_F + lane]);

    __shared__ float sp[4][GCN_F];
    sp[wave][lane] = s;
    __syncthreads();
    if (wave == 0) {
        float tot = sp[0][lane] + sp[1][lane] + sp[2][lane] + sp[3][lane];
        float cntf = (float)(i1 - i0);
        sp[0][lane] = tot / fmaxf(cntf, 1.f);
    }
    __syncthreads();
    if (tid < GCN_C) {
        float o = bl[tid];
#pragma unroll
        for (int j = 0; j < GCN_F; ++j) o += sp[0][j] * Wl[j * GCN_C + tid];
        out[g * GCN_C + tid] = o;
    }
}

// --------------------------------------------------------------------------
extern "C" void kernel_launch(void* const* d_in, const int* in_sizes, int n_in,
                              void* d_out, int out_size, void* d_ws, size_t ws_size,
                              hipStream_t stream) {
    const float* x     = (const float*)d_in[0];
    const int*   ei    = (const int*)d_in[1];
    const float* ew    = (const float*)d_in[2];
    const int*   batch = (const int*)d_in[3];
    const float* W1r   = (const float*)d_in[4];
    const float* W1s   = (const float*)d_in[5];
    const float* b1    = (const float*)d_in[6];
    const float* W2r   = (const float*)d_in[7];
    const float* W2s   = (const float*)d_in[8];
    const float* b2    = (const float*)d_in[9];
    const float* W3r   = (const float*)d_in[10];
    const float* W3s   = (const float*)d_in[11];
    const float* b3    = (const float*)d_in[12];
    const float* Wl    = (const float*)d_in[13];
    const float* bl    = (const float*)d_in[14];
    float* out = (float*)d_out;

    const int N = in_sizes[0] / GCN_F;   // 100000
    const int E = in_sizes[2];           // 1000000
    const int G = out_size / GCN_C;      // 256
    const int B = (N + NB - 1) / NB;     // 1563 buckets

    const int* src = ei;
    const int* dst = ei + E;

    // workspace layout (16B aligned)
    char* ws = (char*)d_ws;
    size_t off = 0;
    int* bcnt    = (int*)(ws + off);  off += ((size_t)B * 4 + 15) & ~(size_t)15;
    int* bcursor = (int*)(ws + off);  off += ((size_t)B * 4 + 15) & ~(size_t)15;
    int* bstart  = (int*)(ws + off);  off += ((size_t)(B + 1) * 4 + 15) & ~(size_t)15;
    int2* ebuf   = (int2*)(ws + off); off += (size_t)E * 8;
    unsigned short* buf0 = (unsigned short*)(ws + off); off += (size_t)N * GCN_F * 2;
    unsigned short* buf1 = (unsigned short*)(ws + off); off += (size_t)N * GCN_F * 2;

    int eblocks = (E + 255) / 256;

    hipMemsetAsync(bcnt, 0, ((size_t)B * 4 + 15 & ~(size_t)15) * 2, stream);  // bcnt+bcursor
    bhist_kernel<<<eblocks, 256, 0, stream>>>(dst, bcnt, E);
    bscan_kernel<<<1, 64, 0, stream>>>(bcnt, bstart, B);
    scatterA_kernel<<<eblocks, 256, 0, stream>>>(src, dst, ew, bstart, bcursor, ebuf, E);

    cvt_kernel<<<1024, 256, 0, stream>>>(x, buf0, N * GCN_F / 4);

    // layer 1: buf0 -> buf1 ; layer 2: buf1 -> buf0 ; layer 3: buf0 -> buf1
    layer_fused<<<B, 256, 0, stream>>>(buf0, bstart, ebuf, W1r, W1s, b1, buf1, N);
    layer_fused<<<B, 256, 0, stream>>>(buf1, bstart, ebuf, W2r, W2s, b2, buf0, N);
    layer_fused<<<B, 256, 0, stream>>>(buf0, bstart, ebuf, W3r, W3s, b3, buf1, N);

    pool_kernel<<<G, 256, 0, stream>>>(buf1, batch, Wl, bl, out, N);
}

// Round 5
// 1461.600 us; speedup vs baseline: 1.1694x; 1.1694x over previous
//
#include <hip/hip_runtime.h>

// GCNe: 3-layer edge-weighted GCN + mean pool + linear head.
// N=100000, E=1000000, F=H=64, G=256, C=10.
//
// R5: bucket edges by (dst>>6, e&7) (8 sub-buckets/bucket kills cursor
// contention; sub-buckets contiguous). Per layer: spmm_bucket (block = 64-node
// bucket, LDS f32 agg via native ds_add_f32 atomics, edge-parallel) then
// separate MFMA bf16 GEMM relu(agg@Wr + x@Ws + b). bf16 node features.

#define GCN_F 64
#define GCN_C 10
#define NB 64            // nodes per bucket
#define SUB 8            // sub-buckets per bucket (scatter cursor spreading)

typedef __attribute__((ext_vector_type(8))) short bf16x8;
typedef __attribute__((ext_vector_type(4))) float f32x4;

__device__ __forceinline__ unsigned short f2b(float v) {
    union { float f; unsigned int u; } c; c.f = v;
    unsigned int u = c.u;
    return (unsigned short)((u + 0x7FFFu + ((u >> 16) & 1u)) >> 16);  // RNE
}
__device__ __forceinline__ float b2f(unsigned short u) {
    union { unsigned int u; float f; } c; c.u = ((unsigned int)u) << 16; return c.f;
}

// ------------------------------------------------------ sub-bucket histogram
__global__ __launch_bounds__(256) void bhist_kernel(const int* __restrict__ dst,
                                                    int* __restrict__ scnt, int E) {
    int e = blockIdx.x * blockDim.x + threadIdx.x;
    if (e < E) atomicAdd(&scnt[(dst[e] >> 6) * SUB + (e & (SUB - 1))], 1);
}

// ------------------------------------------------ sub-bucket scan (one wave)
__global__ void bscan_kernel(const int* __restrict__ scnt, int* __restrict__ sstart,
                             int nb) {
    int lane = threadIdx.x;
    int carry = 0;
    for (int base = 0; base < nb; base += 64) {
        int i = base + lane;
        int v = (i < nb) ? scnt[i] : 0;
        int sc = v;
#pragma unroll
        for (int off = 1; off < 64; off <<= 1) {
            int t = __shfl_up(sc, off);
            if (lane >= off) sc += t;
        }
        if (i < nb) sstart[i] = carry + sc - v;   // exclusive
        carry += __shfl(sc, 63);
    }
    if (lane == 0) sstart[nb] = carry;            // = E
}

// -------------------------------------------------- scatter into sub-buckets
// packed.x = src | (dst&63)<<26 ; packed.y = bits(ew)
__global__ __launch_bounds__(256) void scatterA_kernel(
    const int* __restrict__ src, const int* __restrict__ dst,
    const float* __restrict__ ew, const int* __restrict__ sstart,
    int* __restrict__ scursor, int2* __restrict__ ebuf, int E) {
    int e = blockIdx.x * blockDim.x + threadIdx.x;
    if (e < E) {
        int d = dst[e];
        int key = (d >> 6) * SUB + (e & (SUB - 1));
        int pos = sstart[key] + atomicAdd(&scursor[key], 1);
        int2 rec;
        rec.x = src[e] | ((d & 63) << 26);
        rec.y = __float_as_int(ew[e]);
        ebuf[pos] = rec;
    }
}

// ----------------------------------------------------- fp32 -> bf16 convert
__global__ __launch_bounds__(256) void cvt_kernel(const float* __restrict__ in,
                                                  unsigned short* __restrict__ out,
                                                  int n4) {
    int stride = gridDim.x * blockDim.x;
    for (int i = blockIdx.x * blockDim.x + threadIdx.x; i < n4; i += stride) {
        float4 v = reinterpret_cast<const float4*>(in)[i];
        ushort4 o;
        o.x = f2b(v.x); o.y = f2b(v.y); o.z = f2b(v.z); o.w = f2b(v.w);
        reinterpret_cast<ushort4*>(out)[i] = o;
    }
}

// ------------------------------ SpMM per bucket: agg[dst&63][:] += ew*x[src]
// Block = one 64-node bucket. 4 waves split the bucket's edge range.
// lane = feature. LDS f32 agg, native shared-memory atomicAdd (ds_add_f32).
__global__ __launch_bounds__(256) void spmm_bucket(
    const unsigned short* __restrict__ xin, const int* __restrict__ sstart,
    const int2* __restrict__ ebuf, unsigned short* __restrict__ aggOut, int n)
{
    __shared__ float agg[NB][GCN_F];              // 16 KB
    int tid = threadIdx.x, lane = tid & 63, wave = tid >> 6;
    int bkt = blockIdx.x;

    for (int i = tid; i < NB * GCN_F; i += 256) ((float*)agg)[i] = 0.f;
    __syncthreads();

    int e0 = sstart[bkt * SUB], e1 = sstart[bkt * SUB + SUB];
    int cnt = e1 - e0;
    int per = (cnt + 3) >> 2;
    int q0 = e0 + wave * per;
    int q1 = min(q0 + per, e1);

    int i = q0;
    for (; i + 8 <= q1; i += 8) {
        int2 er[8];
#pragma unroll
        for (int q = 0; q < 8; ++q) er[q] = ebuf[i + q];
        float r[8];
#pragma unroll
        for (int q = 0; q < 8; ++q) {
            int s = er[q].x & 0x3FFFFFF;
            r[q] = b2f(xin[(size_t)s * GCN_F + lane]) * __int_as_float(er[q].y);
        }
#pragma unroll
        for (int q = 0; q < 8; ++q) {
            int d = (unsigned)er[q].x >> 26;
            atomicAdd(&agg[d][lane], r[q]);       // ds_add_f32
        }
    }
    for (; i < q1; ++i) {
        int2 er = ebuf[i];
        int s = er.x & 0x3FFFFFF, d = (unsigned)er.x >> 26;
        float v = b2f(xin[(size_t)s * GCN_F + lane]) * __int_as_float(er.y);
        atomicAdd(&agg[d][lane], v);
    }
    __syncthreads();

    // write bucket agg rows to global as bf16 (coalesced; guard tail bucket)
    for (int j = tid; j < NB * GCN_F; j += 256) {
        int grow = bkt * NB + (j >> 6);
        if (grow < n) aggOut[(size_t)bkt * NB * GCN_F + j] = f2b(((float*)agg)[j]);
    }
}

// ---------------------- GEMM: h = relu(agg @ Wr + x @ Ws + b), bf16 via MFMA
// 16x16x32 bf16 MFMA. A: lane holds row=l&15, k=(l>>4)*8+j. B: col=l&15, same k.
// C/D: col=lane&15, row=(lane>>4)*4+reg.   (verified in R3, absmax 0.0156)
__global__ __launch_bounds__(256) void gemm_kernel(
    const unsigned short* __restrict__ agg, const unsigned short* __restrict__ xin,
    const float* __restrict__ Wr, const float* __restrict__ Ws,
    const float* __restrict__ b, unsigned short* __restrict__ out, int n)
{
    __shared__ __align__(16) unsigned short bfrag[2][2][4][64][8];   // 16 KB
    int tid = threadIdx.x;
    for (int i = tid; i < 8192; i += 256) {
        int op = i >> 12;
        int ks = (i >> 11) & 1;
        int ct = (i >> 9) & 3;
        int l  = (i >> 3) & 63;
        int j  = i & 7;
        int k   = ks * 32 + (l >> 4) * 8 + j;
        int col = ct * 16 + (l & 15);
        const float* W = op ? Ws : Wr;
        ((unsigned short*)bfrag)[i] = f2b(W[k * GCN_F + col]);
    }
    __syncthreads();

    int lane = tid & 63, wave = tid >> 6;
    int l15 = lane & 15, lhi = lane >> 4;

    bf16x8 B[2][2][4];
#pragma unroll
    for (int op = 0; op < 2; ++op)
#pragma unroll
        for (int ks = 0; ks < 2; ++ks)
#pragma unroll
            for (int ct = 0; ct < 4; ++ct)
                B[op][ks][ct] = *reinterpret_cast<const bf16x8*>(&bfrag[op][ks][ct][lane][0]);

    float bias[4];
#pragma unroll
    for (int ct = 0; ct < 4; ++ct) bias[ct] = b[ct * 16 + l15];

    int ntiles = (n + 15) >> 4;
    for (int t = blockIdx.x * 4 + wave; t < ntiles; t += gridDim.x * 4) {
        int row = t * 16 + l15;
        int arow = min(row, n - 1);
        const unsigned short* ap = agg + (size_t)arow * GCN_F + lhi * 8;
        const unsigned short* xp = xin + (size_t)arow * GCN_F + lhi * 8;
        bf16x8 a0 = *reinterpret_cast<const bf16x8*>(ap);
        bf16x8 a1 = *reinterpret_cast<const bf16x8*>(ap + 32);
        bf16x8 x0 = *reinterpret_cast<const bf16x8*>(xp);
        bf16x8 x1 = *reinterpret_cast<const bf16x8*>(xp + 32);
#pragma unroll
        for (int ct = 0; ct < 4; ++ct) {
            f32x4 acc = {0.f, 0.f, 0.f, 0.f};
            acc = __builtin_amdgcn_mfma_f32_16x16x32_bf16(a0, B[0][0][ct], acc, 0, 0, 0);
            acc = __builtin_amdgcn_mfma_f32_16x16x32_bf16(a1, B[0][1][ct], acc, 0, 0, 0);
            acc = __builtin_amdgcn_mfma_f32_16x16x32_bf16(x0, B[1][0][ct], acc, 0, 0, 0);
            acc = __builtin_amdgcn_mfma_f32_16x16x32_bf16(x1, B[1][1][ct], acc, 0, 0, 0);
            int col = ct * 16 + l15;
#pragma unroll
            for (int r = 0; r < 4; ++r) {
                int orow = t * 16 + lhi * 4 + r;
                if (orow < n) {
                    float v = fmaxf(acc[r] + bias[ct], 0.f);
                    out[(size_t)orow * GCN_F + col] = f2b(v);
                }
            }
        }
    }
}

// ------------------------------------------------- mean pool + linear head
__global__ __launch_bounds__(256) void pool_kernel(
    const unsigned short* __restrict__ h, const int* __restrict__ batch,
    const float* __restrict__ Wl, const float* __restrict__ bl,
    float* __restrict__ out, int n)
{
    int g    = blockIdx.x;
    int tid  = threadIdx.x;
    int lane = tid & 63;
    int wave = tid >> 6;

    int i0, i1;
    {
        int lo = 0, hi = n;
        while (lo < hi) { int mid = (lo + hi) >> 1; if (batch[mid] < g) lo = mid + 1; else hi = mid; }
        i0 = lo;
        lo = i0; hi = n;
        while (lo < hi) { int mid = (lo + hi) >> 1; if (batch[mid] < g + 1) lo = mid + 1; else hi = mid; }
        i1 = lo;
    }

    float s = 0.f;
    for (int i = i0 + wave; i < i1; i += 4) s += b2f(h[(size_t)i * GCN_F + lane]);

    __shared__ float sp[4][GCN_F];
    sp[wave][lane] = s;
    __syncthreads();
    if (wave == 0) {
        float tot = sp[0][lane] + sp[1][lane] + sp[2][lane] + sp[3][lane];
        float cntf = (float)(i1 - i0);
        sp[0][lane] = tot / fmaxf(cntf, 1.f);
    }
    __syncthreads();
    if (tid < GCN_C) {
        float o = bl[tid];
#pragma unroll
        for (int j = 0; j < GCN_F; ++j) o += sp[0][j] * Wl[j * GCN_C + tid];
        out[g * GCN_C + tid] = o;
    }
}

// --------------------------------------------------------------------------
extern "C" void kernel_launch(void* const* d_in, const int* in_sizes, int n_in,
                              void* d_out, int out_size, void* d_ws, size_t ws_size,
                              hipStream_t stream) {
    const float* x     = (const float*)d_in[0];
    const int*   ei    = (const int*)d_in[1];
    const float* ew    = (const float*)d_in[2];
    const int*   batch = (const int*)d_in[3];
    const float* W1r   = (const float*)d_in[4];
    const float* W1s   = (const float*)d_in[5];
    const float* b1    = (const float*)d_in[6];
    const float* W2r   = (const float*)d_in[7];
    const float* W2s   = (const float*)d_in[8];
    const float* b2    = (const float*)d_in[9];
    const float* W3r   = (const float*)d_in[10];
    const float* W3s   = (const float*)d_in[11];
    const float* b3    = (const float*)d_in[12];
    const float* Wl    = (const float*)d_in[13];
    const float* bl    = (const float*)d_in[14];
    float* out = (float*)d_out;

    const int N = in_sizes[0] / GCN_F;   // 100000
    const int E = in_sizes[2];           // 1000000
    const int G = out_size / GCN_C;      // 256
    const int B = (N + NB - 1) / NB;     // 1563 buckets
    const int NS = B * SUB;              // 12504 sub-buckets

    const int* src = ei;
    const int* dst = ei + E;

    // workspace layout (16B aligned)
    char* ws = (char*)d_ws;
    size_t off = 0;
    size_t scsz = ((size_t)NS * 4 + 15) & ~(size_t)15;
    int* scnt    = (int*)(ws + off);  off += scsz;
    int* scursor = (int*)(ws + off);  off += scsz;
    int* sstart  = (int*)(ws + off);  off += ((size_t)(NS + 1) * 4 + 15) & ~(size_t)15;
    int2* ebuf   = (int2*)(ws + off); off += (size_t)E * 8;
    unsigned short* buf0 = (unsigned short*)(ws + off); off += (size_t)N * GCN_F * 2;
    unsigned short* buf1 = (unsigned short*)(ws + off); off += (size_t)N * GCN_F * 2;
    unsigned short* aggB = (unsigned short*)(ws + off); off += (size_t)B * NB * GCN_F * 2;

    int eblocks = (E + 255) / 256;

    hipMemsetAsync(scnt, 0, scsz * 2, stream);   // scnt + scursor
    bhist_kernel<<<eblocks, 256, 0, stream>>>(dst, scnt, E);
    bscan_kernel<<<1, 64, 0, stream>>>(scnt, sstart, NS);
    scatterA_kernel<<<eblocks, 256, 0, stream>>>(src, dst, ew, sstart, scursor, ebuf, E);

    cvt_kernel<<<1024, 256, 0, stream>>>(x, buf0, N * GCN_F / 4);

    const int GBLK = 800;
    // layer 1: buf0 -> buf1
    spmm_bucket<<<B, 256, 0, stream>>>(buf0, sstart, ebuf, aggB, N);
    gemm_kernel<<<GBLK, 256, 0, stream>>>(aggB, buf0, W1r, W1s, b1, buf1, N);
    // layer 2: buf1 -> buf0
    spmm_bucket<<<B, 256, 0, stream>>>(buf1, sstart, ebuf, aggB, N);
    gemm_kernel<<<GBLK, 256, 0, stream>>>(aggB, buf1, W2r, W2s, b2, buf0, N);
    // layer 3: buf0 -> buf1
    spmm_bucket<<<B, 256, 0, stream>>>(buf0, sstart, ebuf, aggB, N);
    gemm_kernel<<<GBLK, 256, 0, stream>>>(aggB, buf0, W3r, W3s, b3, buf1, N);

    pool_kernel<<<G, 256, 0, stream>>>(buf1, batch, Wl, bl, out, N);
}

// Round 7
// 349.331 us; speedup vs baseline: 4.8926x; 4.1840x over previous
//
#include <hip/hip_runtime.h>

// GCNe: 3-layer edge-weighted GCN + mean pool + linear head.
// N=100000, E=1000000, F=H=64, G=256, C=10.
//
// R7 (= R6 with ds_bpermute instead of ds_swizzle): exact CSR via
// coarse-bucket (dst>>9) scatter + per-bucket LDS counting sort (emits sorted
// edges AND node offsets). SpMM: wave = 8 nodes x 8 lanes, lane = 8 features
// (int4 16B gathers, 8 rows in flight), edge records broadcast within 8-lane
// groups via ds_bpermute. Then MFMA bf16 GEMM.

#define GCN_F 64
#define GCN_C 10
#define CB_SHIFT 9
#define CB_NODES 512          // nodes per coarse bucket
#define SUBW 32               // sub-cursors per coarse bucket
#define CAP 7168              // max edges staged per bucket (mean 5102, +29 sigma)

typedef __attribute__((ext_vector_type(8))) short bf16x8;
typedef __attribute__((ext_vector_type(4))) float f32x4;

__device__ __forceinline__ unsigned short f2b(float v) {
    union { float f; unsigned int u; } c; c.f = v;
    unsigned int u = c.u;
    return (unsigned short)((u + 0x7FFFu + ((u >> 16) & 1u)) >> 16);  // RNE
}
__device__ __forceinline__ float b2f(unsigned short u) {
    union { unsigned int u; float f; } c; c.u = ((unsigned int)u) << 16; return c.f;
}

// --------------------------- sub-bucket histogram (LDS-staged, 4096 edges/blk)
__global__ __launch_bounds__(256) void histS_kernel(const int* __restrict__ dst,
                                                    int* __restrict__ scnt,
                                                    int E, int NS) {
    __shared__ int h[6400];
    int tid = threadIdx.x;
    for (int i = tid; i < NS; i += 256) h[i] = 0;
    __syncthreads();
    int e0 = blockIdx.x * 4096 + tid;
#pragma unroll
    for (int k = 0; k < 16; ++k) {
        int e = e0 + k * 256;
        if (e < E) atomicAdd(&h[(dst[e] >> CB_SHIFT) * SUBW + (e & (SUBW - 1))], 1);
    }
    __syncthreads();
    for (int i = tid; i < NS; i += 256)
        if (h[i]) atomicAdd(&scnt[i], h[i]);
}

// ------------------------------------------------ sub-bucket scan (one wave)
__global__ void bscan_kernel(const int* __restrict__ scnt, int* __restrict__ sstart,
                             int nb) {
    int lane = threadIdx.x;
    int carry = 0;
    for (int base = 0; base < nb; base += 64) {
        int i = base + lane;
        int v = (i < nb) ? scnt[i] : 0;
        int sc = v;
#pragma unroll
        for (int off = 1; off < 64; off <<= 1) {
            int t = __shfl_up(sc, off);
            if (lane >= off) sc += t;
        }
        if (i < nb) sstart[i] = carry + sc - v;   // exclusive
        carry += __shfl(sc, 63);
    }
    if (lane == 0) sstart[nb] = carry;            // = E
}

// ----------------------------------------- scatter into coarse sub-buckets
// rec.x = src | (dst&511)<<17 ; rec.y = bits(ew)   (src < 2^17)
__global__ __launch_bounds__(256) void scatterC_kernel(
    const int* __restrict__ src, const int* __restrict__ dst,
    const float* __restrict__ ew, const int* __restrict__ sstart,
    int* __restrict__ scursor, int2* __restrict__ ebufA, int E) {
    int e = blockIdx.x * blockDim.x + threadIdx.x;
    if (e < E) {
        int d = dst[e];
        int key = (d >> CB_SHIFT) * SUBW + (e & (SUBW - 1));
        int pos = sstart[key] + atomicAdd(&scursor[key], 1);
        ebufA[pos] = make_int2(src[e] | ((d & (CB_NODES - 1)) << 17),
                               __float_as_int(ew[e]));
    }
}

// -------------- per-bucket LDS counting sort -> sorted edges + node offsets
__global__ __launch_bounds__(256) void sortCB_kernel(
    const int2* __restrict__ ebufA, const int* __restrict__ sstart,
    int2* __restrict__ ebufS, int* __restrict__ offsets, int N, int E) {
    __shared__ int2 rec[CAP];                 // 56 KB
    __shared__ int cnt[CB_NODES];
    __shared__ int cur[CB_NODES];
    __shared__ int sbuf[256];
    int cb = blockIdx.x, tid = threadIdx.x;
    int e0 = sstart[cb * SUBW], e1 = sstart[cb * SUBW + SUBW];
    int m = min(e1 - e0, CAP);

    for (int i = tid; i < m; i += 256) rec[i] = ebufA[e0 + i];
    for (int i = tid; i < CB_NODES; i += 256) cnt[i] = 0;
    __syncthreads();
    for (int i = tid; i < m; i += 256)
        atomicAdd(&cnt[(unsigned)rec[i].x >> 17], 1);
    __syncthreads();

    // exclusive scan over 512 counts (thread owns 2)
    int c0 = cnt[2 * tid], c1 = cnt[2 * tid + 1];
    int part = c0 + c1;
    sbuf[tid] = part;
    __syncthreads();
    for (int off = 1; off < 256; off <<= 1) {
        int t = (tid >= off) ? sbuf[tid - off] : 0;
        __syncthreads();
        sbuf[tid] += t;
        __syncthreads();
    }
    int excl = sbuf[tid] - part;
    int pre0 = excl, pre1 = excl + c0;
    cur[2 * tid] = pre0;
    cur[2 * tid + 1] = pre1;
    int g0 = cb * CB_NODES + 2 * tid;
    if (g0 <= N)     offsets[g0]     = e0 + pre0;
    if (g0 + 1 <= N) offsets[g0 + 1] = e0 + pre1;
    __syncthreads();

    for (int i = tid; i < m; i += 256) {
        int d9 = (unsigned)rec[i].x >> 17;
        int pos = atomicAdd(&cur[d9], 1);
        ebufS[e0 + pos] = make_int2(rec[i].x & 0x1FFFF, rec[i].y);
    }
}

// ----------------------------------------------------- fp32 -> bf16 convert
__global__ __launch_bounds__(256) void cvt_kernel(const float* __restrict__ in,
                                                  unsigned short* __restrict__ out,
                                                  int n4) {
    int stride = gridDim.x * blockDim.x;
    for (int i = blockIdx.x * blockDim.x + threadIdx.x; i < n4; i += stride) {
        float4 v = reinterpret_cast<const float4*>(in)[i];
        ushort4 o;
        o.x = f2b(v.x); o.y = f2b(v.y); o.z = f2b(v.z); o.w = f2b(v.w);
        reinterpret_cast<ushort4*>(out)[i] = o;
    }
}

// --------------------- SpMM: wave = 8 nodes x 8 lanes; lane = 8 features
// Edge chunk: 8 records per node loaded coalesced; ds_bpermute broadcasts
// record j to the group's 8 lanes; gathers are int4 (16B) -> 1KB/instr.
__global__ __launch_bounds__(256) void spmm8_kernel(
    const unsigned short* __restrict__ xin, const int* __restrict__ offsets,
    const int2* __restrict__ ebufS, unsigned short* __restrict__ aggOut, int n)
{
    int tid = threadIdx.x, lane = tid & 63, wave = tid >> 6;
    int l8 = lane & 7;
    int gbase = (lane & 56) << 2;           // byte addr of group's lane 0
    int nbase0 = (blockIdx.x * 4 + wave) * 8;
    int nstride = gridDim.x * 32;

    for (int nb = nbase0; nb < n; nb += nstride) {
        int node = nb + (lane >> 3);
        bool nv = node < n;
        int p0 = 0, p1 = 0;
        if (nv) { p0 = offsets[node]; p1 = offsets[node + 1]; }
        float acc[8] = {0.f, 0.f, 0.f, 0.f, 0.f, 0.f, 0.f, 0.f};

        for (int c = 0;; ++c) {
            int idx = p0 + c * 8 + l8;
            bool v = idx < p1;
            if (!__any(v)) break;
            int2 er = ebufS[v ? idx : 0];
            int s  = v ? er.x : 0;
            int wb = v ? er.y : 0;

            int sj[8], wj[8];
#pragma unroll
            for (int j = 0; j < 8; ++j) {
                sj[j] = __builtin_amdgcn_ds_bpermute(gbase + (j << 2), s);
                wj[j] = __builtin_amdgcn_ds_bpermute(gbase + (j << 2), wb);
            }
#pragma unroll
            for (int j = 0; j < 8; ++j) {
                float wf = __int_as_float(wj[j]);
                const int4 r = *reinterpret_cast<const int4*>(
                    xin + ((size_t)sj[j] << 6) + l8 * 8);
                acc[0] = fmaf(__int_as_float(r.x << 16),          wf, acc[0]);
                acc[1] = fmaf(__int_as_float(r.x & 0xFFFF0000),   wf, acc[1]);
                acc[2] = fmaf(__int_as_float(r.y << 16),          wf, acc[2]);
                acc[3] = fmaf(__int_as_float(r.y & 0xFFFF0000),   wf, acc[3]);
                acc[4] = fmaf(__int_as_float(r.z << 16),          wf, acc[4]);
                acc[5] = fmaf(__int_as_float(r.z & 0xFFFF0000),   wf, acc[5]);
                acc[6] = fmaf(__int_as_float(r.w << 16),          wf, acc[6]);
                acc[7] = fmaf(__int_as_float(r.w & 0xFFFF0000),   wf, acc[7]);
            }
        }

        if (nv) {
            int4 o;
            o.x = (int)f2b(acc[0]) | ((int)f2b(acc[1]) << 16);
            o.y = (int)f2b(acc[2]) | ((int)f2b(acc[3]) << 16);
            o.z = (int)f2b(acc[4]) | ((int)f2b(acc[5]) << 16);
            o.w = (int)f2b(acc[6]) | ((int)f2b(acc[7]) << 16);
            *reinterpret_cast<int4*>(aggOut + ((size_t)node << 6) + l8 * 8) = o;
        }
    }
}

// ---------------------- GEMM: h = relu(agg @ Wr + x @ Ws + b), bf16 via MFMA
// 16x16x32 bf16 MFMA. A: lane holds row=l&15, k=(l>>4)*8+j. B: col=l&15, same k.
// C/D: col=lane&15, row=(lane>>4)*4+reg.   (verified R3, absmax 0.0156)
__global__ __launch_bounds__(256) void gemm_kernel(
    const unsigned short* __restrict__ agg, const unsigned short* __restrict__ xin,
    const float* __restrict__ Wr, const float* __restrict__ Ws,
    const float* __restrict__ b, unsigned short* __restrict__ out, int n)
{
    __shared__ __align__(16) unsigned short bfrag[2][2][4][64][8];   // 16 KB
    int tid = threadIdx.x;
    for (int i = tid; i < 8192; i += 256) {
        int op = i >> 12;
        int ks = (i >> 11) & 1;
        int ct = (i >> 9) & 3;
        int l  = (i >> 3) & 63;
        int j  = i & 7;
        int k   = ks * 32 + (l >> 4) * 8 + j;
        int col = ct * 16 + (l & 15);
        const float* W = op ? Ws : Wr;
        ((unsigned short*)bfrag)[i] = f2b(W[k * GCN_F + col]);
    }
    __syncthreads();

    int lane = tid & 63, wave = tid >> 6;
    int l15 = lane & 15, lhi = lane >> 4;

    bf16x8 B[2][2][4];
#pragma unroll
    for (int op = 0; op < 2; ++op)
#pragma unroll
        for (int ks = 0; ks < 2; ++ks)
#pragma unroll
            for (int ct = 0; ct < 4; ++ct)
                B[op][ks][ct] = *reinterpret_cast<const bf16x8*>(&bfrag[op][ks][ct][lane][0]);

    float bias[4];
#pragma unroll
    for (int ct = 0; ct < 4; ++ct) bias[ct] = b[ct * 16 + l15];

    int ntiles = (n + 15) >> 4;
    for (int t = blockIdx.x * 4 + wave; t < ntiles; t += gridDim.x * 4) {
        int row = t * 16 + l15;
        int arow = min(row, n - 1);
        const unsigned short* ap = agg + (size_t)arow * GCN_F + lhi * 8;
        const unsigned short* xp = xin + (size_t)arow * GCN_F + lhi * 8;
        bf16x8 a0 = *reinterpret_cast<const bf16x8*>(ap);
        bf16x8 a1 = *reinterpret_cast<const bf16x8*>(ap + 32);
        bf16x8 x0 = *reinterpret_cast<const bf16x8*>(xp);
        bf16x8 x1 = *reinterpret_cast<const bf16x8*>(xp + 32);
#pragma unroll
        for (int ct = 0; ct < 4; ++ct) {
            f32x4 acc = {0.f, 0.f, 0.f, 0.f};
            acc = __builtin_amdgcn_mfma_f32_16x16x32_bf16(a0, B[0][0][ct], acc, 0, 0, 0);
            acc = __builtin_amdgcn_mfma_f32_16x16x32_bf16(a1, B[0][1][ct], acc, 0, 0, 0);
            acc = __builtin_amdgcn_mfma_f32_16x16x32_bf16(x0, B[1][0][ct], acc, 0, 0, 0);
            acc = __builtin_amdgcn_mfma_f32_16x16x32_bf16(x1, B[1][1][ct], acc, 0, 0, 0);
            int col = ct * 16 + l15;
#pragma unroll
            for (int r = 0; r < 4; ++r) {
                int orow = t * 16 + lhi * 4 + r;
                if (orow < n) {
                    float v = fmaxf(acc[r] + bias[ct], 0.f);
                    out[(size_t)orow * GCN_F + col] = f2b(v);
                }
            }
        }
    }
}

// ------------------------------------------------- mean pool + linear head
__global__ __launch_bounds__(256) void pool_kernel(
    const unsigned short* __restrict__ h, const int* __restrict__ batch,
    const float* __restrict__ Wl, const float* __restrict__ bl,
    float* __restrict__ out, int n)
{
    int g    = blockIdx.x;
    int tid  = threadIdx.x;
    int lane = tid & 63;
    int wave = tid >> 6;

    int i0, i1;
    {
        int lo = 0, hi = n;
        while (lo < hi) { int mid = (lo + hi) >> 1; if (batch[mid] < g) lo = mid + 1; else hi = mid; }
        i0 = lo;
        lo = i0; hi = n;
        while (lo < hi) { int mid = (lo + hi) >> 1; if (batch[mid] < g + 1) lo = mid + 1; else hi = mid; }
        i1 = lo;
    }

    float s = 0.f;
    for (int i = i0 + wave; i < i1; i += 4) s += b2f(h[(size_t)i * GCN_F + lane]);

    __shared__ float sp[4][GCN_F];
    sp[wave][lane] = s;
    __syncthreads();
    if (wave == 0) {
        float tot = sp[0][lane] + sp[1][lane] + sp[2][lane] + sp[3][lane];
        float cntf = (float)(i1 - i0);
        sp[0][lane] = tot / fmaxf(cntf, 1.f);
    }
    __syncthreads();
    if (tid < GCN_C) {
        float o = bl[tid];
#pragma unroll
        for (int j = 0; j < GCN_F; ++j) o += sp[0][j] * Wl[j * GCN_C + tid];
        out[g * GCN_C + tid] = o;
    }
}

// --------------------------------------------------------------------------
extern "C" void kernel_launch(void* const* d_in, const int* in_sizes, int n_in,
                              void* d_out, int out_size, void* d_ws, size_t ws_size,
                              hipStream_t stream) {
    const float* x     = (const float*)d_in[0];
    const int*   ei    = (const int*)d_in[1];
    const float* ew    = (const float*)d_in[2];
    const int*   batch = (const int*)d_in[3];
    const float* W1r   = (const float*)d_in[4];
    const float* W1s   = (const float*)d_in[5];
    const float* b1    = (const float*)d_in[6];
    const float* W2r   = (const float*)d_in[7];
    const float* W2s   = (const float*)d_in[8];
    const float* b2    = (const float*)d_in[9];
    const float* W3r   = (const float*)d_in[10];
    const float* W3s   = (const float*)d_in[11];
    const float* b3    = (const float*)d_in[12];
    const float* Wl    = (const float*)d_in[13];
    const float* bl    = (const float*)d_in[14];
    float* out = (float*)d_out;

    const int N = in_sizes[0] / GCN_F;   // 100000
    const int E = in_sizes[2];           // 1000000
    const int G = out_size / GCN_C;      // 256
    const int B9 = (N + CB_NODES - 1) / CB_NODES;  // 196 coarse buckets
    const int NS = B9 * SUBW;                      // 6272 sub-buckets

    const int* src = ei;
    const int* dst = ei + E;

    // workspace layout (16B aligned)
    char* ws = (char*)d_ws;
    size_t off = 0;
    size_t scsz = ((size_t)NS * 4 + 15) & ~(size_t)15;
    int* scnt    = (int*)(ws + off);  off += scsz;
    int* scursor = (int*)(ws + off);  off += scsz;
    int* sstart  = (int*)(ws + off);  off += ((size_t)(NS + 1) * 4 + 15) & ~(size_t)15;
    int* offsets = (int*)(ws + off);  off += ((size_t)(N + 1) * 4 + 15) & ~(size_t)15;
    int2* ebufA  = (int2*)(ws + off); off += (size_t)E * 8;
    int2* ebufS  = (int2*)(ws + off); off += (size_t)E * 8;
    unsigned short* buf0 = (unsigned short*)(ws + off); off += (size_t)N * GCN_F * 2;
    unsigned short* buf1 = (unsigned short*)(ws + off); off += (size_t)N * GCN_F * 2;
    unsigned short* aggB = (unsigned short*)(ws + off); off += (size_t)N * GCN_F * 2;

    int eblocks = (E + 255) / 256;
    int hblocks = (E + 4095) / 4096;

    hipMemsetAsync(scnt, 0, scsz * 2, stream);   // scnt + scursor
    histS_kernel<<<hblocks, 256, 0, stream>>>(dst, scnt, E, NS);
    bscan_kernel<<<1, 64, 0, stream>>>(scnt, sstart, NS);
    scatterC_kernel<<<eblocks, 256, 0, stream>>>(src, dst, ew, sstart, scursor, ebufA, E);
    sortCB_kernel<<<B9, 256, 0, stream>>>(ebufA, sstart, ebufS, offsets, N, E);

    cvt_kernel<<<1024, 256, 0, stream>>>(x, buf0, N * GCN_F / 4);

    const int SBLK = 1024, GBLK = 800;
    // layer 1: buf0 -> buf1
    spmm8_kernel<<<SBLK, 256, 0, stream>>>(buf0, offsets, ebufS, aggB, N);
    gemm_kernel<<<GBLK, 256, 0, stream>>>(aggB, buf0, W1r, W1s, b1, buf1, N);
    // layer 2: buf1 -> buf0
    spmm8_kernel<<<SBLK, 256, 0, stream>>>(buf1, offsets, ebufS, aggB, N);
    gemm_kernel<<<GBLK, 256, 0, stream>>>(aggB, buf1, W2r, W2s, b2, buf0, N);
    // layer 3: buf0 -> buf1
    spmm8_kernel<<<SBLK, 256, 0, stream>>>(buf0, offsets, ebufS, aggB, N);
    gemm_kernel<<<GBLK, 256, 0, stream>>>(aggB, buf0, W3r, W3s, b3, buf1, N);

    pool_kernel<<<G, 256, 0, stream>>>(buf1, batch, Wl, bl, out, N);
}

// Round 8
// 271.673 us; speedup vs baseline: 6.2911x; 1.2858x over previous
//
#include <hip/hip_runtime.h>

// GCNe: 3-layer edge-weighted GCN + mean pool + linear head.
// N=100000, E=1000000, F=H=64, G=256, C=10.
//
// R8: scatter rebuilt to kill XCD write amplification: per-block LDS counting
// sort over 196 coarse buckets + chunk reservation -> coalesced contiguous-run
// writes (each 64B line written by one block). Then per-bucket LDS counting
// sort (sortCB) -> exact CSR. SpMM: wave = 8 nodes x 8 lanes, int4 gathers,
// ds_bpermute edge broadcast (2048 blocks for full occupancy). MFMA bf16 GEMM.

#define GCN_F 64
#define GCN_C 10
#define CB_SHIFT 9
#define CB_NODES 512          // nodes per coarse bucket
#define NCB_MAX 200           // >= ceil(N/512)=196
#define CAP 7168              // max edges per coarse bucket (mean 5102)
#define SC_CHUNK 2048         // edges per scatter block

typedef __attribute__((ext_vector_type(8))) short bf16x8;
typedef __attribute__((ext_vector_type(4))) float f32x4;

__device__ __forceinline__ unsigned short f2b(float v) {
    union { float f; unsigned int u; } c; c.f = v;
    unsigned int u = c.u;
    return (unsigned short)((u + 0x7FFFu + ((u >> 16) & 1u)) >> 16);  // RNE
}
__device__ __forceinline__ float b2f(unsigned short u) {
    union { unsigned int u; float f; } c; c.u = ((unsigned int)u) << 16; return c.f;
}

// --------------------------- coarse-bucket histogram (LDS-staged)
__global__ __launch_bounds__(256) void histC_kernel(const int* __restrict__ dst,
                                                    int* __restrict__ bcnt,
                                                    int E, int NCB) {
    __shared__ int h[NCB_MAX];
    int tid = threadIdx.x;
    for (int i = tid; i < NCB; i += 256) h[i] = 0;
    __syncthreads();
    int e0 = blockIdx.x * 4096 + tid;
#pragma unroll
    for (int k = 0; k < 16; ++k) {
        int e = e0 + k * 256;
        if (e < E) atomicAdd(&h[dst[e] >> CB_SHIFT], 1);
    }
    __syncthreads();
    for (int i = tid; i < NCB; i += 256)
        if (h[i]) atomicAdd(&bcnt[i], h[i]);
}

// ------------------------------------------------ bucket scan (one wave)
__global__ void bscan_kernel(const int* __restrict__ bcnt, int* __restrict__ gstart,
                             int nb) {
    int lane = threadIdx.x;
    int carry = 0;
    for (int base = 0; base < nb; base += 64) {
        int i = base + lane;
        int v = (i < nb) ? bcnt[i] : 0;
        int sc = v;
#pragma unroll
        for (int off = 1; off < 64; off <<= 1) {
            int t = __shfl_up(sc, off);
            if (lane >= off) sc += t;
        }
        if (i < nb) gstart[i] = carry + sc - v;   // exclusive
        carry += __shfl(sc, 63);
    }
    if (lane == 0) gstart[nb] = carry;            // = E
}

// ------------- scatter: block-local counting sort + chunk-reserved run writes
// rec.x = src | (dst&511)<<17 ; rec.y = bits(ew)
__global__ __launch_bounds__(256) void scatterC_kernel(
    const int* __restrict__ src, const int* __restrict__ dst,
    const float* __restrict__ ew, const int* __restrict__ gstart,
    int* __restrict__ gcursor, int2* __restrict__ ebufA, int E, int NCB) {
    __shared__ int2 recS[SC_CHUNK];     // 16 KB
    __shared__ int gdest[SC_CHUNK];     // 8 KB
    __shared__ int hist[NCB_MAX];
    __shared__ int lstart[NCB_MAX];
    __shared__ int gbase[NCB_MAX];
    __shared__ int cur[NCB_MAX];
    __shared__ int sb[256];

    int tid = threadIdx.x;
    int base = blockIdx.x * SC_CHUNK;
    int m = min(SC_CHUNK, E - base);

    for (int i = tid; i < NCB; i += 256) hist[i] = 0;
    __syncthreads();

    int2 rec[8];
    int bk[8];
#pragma unroll
    for (int k = 0; k < 8; ++k) {
        int e = base + k * 256 + tid;
        if (e < E) {
            int d = dst[e];
            bk[k] = d >> CB_SHIFT;
            rec[k] = make_int2(src[e] | ((d & (CB_NODES - 1)) << 17),
                               __float_as_int(ew[e]));
            atomicAdd(&hist[bk[k]], 1);
        } else bk[k] = -1;
    }
    __syncthreads();

    // block-wide exclusive scan of hist[0..NCB)
    int v = (tid < NCB) ? hist[tid] : 0;
    sb[tid] = v;
    __syncthreads();
    for (int o = 1; o < 256; o <<= 1) {
        int t = (tid >= o) ? sb[tid - o] : 0;
        __syncthreads();
        sb[tid] += t;
        __syncthreads();
    }
    if (tid < NCB) {
        int excl = sb[tid] - v;
        lstart[tid] = excl;
        cur[tid] = excl;
        gbase[tid] = (v > 0) ? atomicAdd(&gcursor[tid], v) : 0;  // reserve run
    }
    __syncthreads();

    // place records into LDS sorted by bucket; record global destination
#pragma unroll
    for (int k = 0; k < 8; ++k) {
        if (bk[k] >= 0) {
            int p = atomicAdd(&cur[bk[k]], 1);
            recS[p] = rec[k];
            gdest[p] = gstart[bk[k]] + gbase[bk[k]] + (p - lstart[bk[k]]);
        }
    }
    __syncthreads();

    // coalesced staged write (consecutive i within a run -> consecutive dest)
    for (int i = tid; i < m; i += 256) ebufA[gdest[i]] = recS[i];
}

// -------------- per-bucket LDS counting sort -> sorted edges + node offsets
__global__ __launch_bounds__(256) void sortCB_kernel(
    const int2* __restrict__ ebufA, const int* __restrict__ gstart,
    int2* __restrict__ ebufS, int* __restrict__ offsets, int N, int E) {
    __shared__ int2 rec[CAP];                 // 56 KB
    __shared__ int cnt[CB_NODES];
    __shared__ int cur[CB_NODES];
    __shared__ int sbuf[256];
    int cb = blockIdx.x, tid = threadIdx.x;
    int e0 = gstart[cb], e1 = gstart[cb + 1];
    int m = min(e1 - e0, CAP);

    for (int i = tid; i < m; i += 256) rec[i] = ebufA[e0 + i];
    for (int i = tid; i < CB_NODES; i += 256) cnt[i] = 0;
    __syncthreads();
    for (int i = tid; i < m; i += 256)
        atomicAdd(&cnt[(unsigned)rec[i].x >> 17], 1);
    __syncthreads();

    // exclusive scan over 512 counts (thread owns 2)
    int c0 = cnt[2 * tid], c1 = cnt[2 * tid + 1];
    int part = c0 + c1;
    sbuf[tid] = part;
    __syncthreads();
    for (int off = 1; off < 256; off <<= 1) {
        int t = (tid >= off) ? sbuf[tid - off] : 0;
        __syncthreads();
        sbuf[tid] += t;
        __syncthreads();
    }
    int excl = sbuf[tid] - part;
    int pre0 = excl, pre1 = excl + c0;
    cur[2 * tid] = pre0;
    cur[2 * tid + 1] = pre1;
    int g0 = cb * CB_NODES + 2 * tid;
    if (g0 <= N)     offsets[g0]     = e0 + pre0;
    if (g0 + 1 <= N) offsets[g0 + 1] = e0 + pre1;
    __syncthreads();

    for (int i = tid; i < m; i += 256) {
        int d9 = (unsigned)rec[i].x >> 17;
        int pos = atomicAdd(&cur[d9], 1);
        ebufS[e0 + pos] = make_int2(rec[i].x & 0x1FFFF, rec[i].y);
    }
}

// ----------------------------------------------------- fp32 -> bf16 convert
__global__ __launch_bounds__(256) void cvt_kernel(const float* __restrict__ in,
                                                  unsigned short* __restrict__ out,
                                                  int n4) {
    int stride = gridDim.x * blockDim.x;
    for (int i = blockIdx.x * blockDim.x + threadIdx.x; i < n4; i += stride) {
        float4 v = reinterpret_cast<const float4*>(in)[i];
        ushort4 o;
        o.x = f2b(v.x); o.y = f2b(v.y); o.z = f2b(v.z); o.w = f2b(v.w);
        reinterpret_cast<ushort4*>(out)[i] = o;
    }
}

// --------------------- SpMM: wave = 8 nodes x 8 lanes; lane = 8 features
__global__ __launch_bounds__(256) void spmm8_kernel(
    const unsigned short* __restrict__ xin, const int* __restrict__ offsets,
    const int2* __restrict__ ebufS, unsigned short* __restrict__ aggOut, int n)
{
    int tid = threadIdx.x, lane = tid & 63, wave = tid >> 6;
    int l8 = lane & 7;
    int gbase = (lane & 56) << 2;           // byte addr of group's lane 0
    int nbase0 = (blockIdx.x * 4 + wave) * 8;
    int nstride = gridDim.x * 32;

    for (int nb = nbase0; nb < n; nb += nstride) {
        int node = nb + (lane >> 3);
        bool nv = node < n;
        int p0 = 0, p1 = 0;
        if (nv) { p0 = offsets[node]; p1 = offsets[node + 1]; }
        float acc[8] = {0.f, 0.f, 0.f, 0.f, 0.f, 0.f, 0.f, 0.f};

        for (int c = 0;; ++c) {
            int idx = p0 + c * 8 + l8;
            bool v = idx < p1;
            if (!__any(v)) break;
            int2 er = ebufS[v ? idx : 0];
            int s  = v ? er.x : 0;
            int wb = v ? er.y : 0;

            int sj[8], wj[8];
#pragma unroll
            for (int j = 0; j < 8; ++j) {
                sj[j] = __builtin_amdgcn_ds_bpermute(gbase + (j << 2), s);
                wj[j] = __builtin_amdgcn_ds_bpermute(gbase + (j << 2), wb);
            }
#pragma unroll
            for (int j = 0; j < 8; ++j) {
                float wf = __int_as_float(wj[j]);
                const int4 r = *reinterpret_cast<const int4*>(
                    xin + ((size_t)sj[j] << 6) + l8 * 8);
                acc[0] = fmaf(__int_as_float(r.x << 16),          wf, acc[0]);
                acc[1] = fmaf(__int_as_float(r.x & 0xFFFF0000),   wf, acc[1]);
                acc[2] = fmaf(__int_as_float(r.y << 16),          wf, acc[2]);
                acc[3] = fmaf(__int_as_float(r.y & 0xFFFF0000),   wf, acc[3]);
                acc[4] = fmaf(__int_as_float(r.z << 16),          wf, acc[4]);
                acc[5] = fmaf(__int_as_float(r.z & 0xFFFF0000),   wf, acc[5]);
                acc[6] = fmaf(__int_as_float(r.w << 16),          wf, acc[6]);
                acc[7] = fmaf(__int_as_float(r.w & 0xFFFF0000),   wf, acc[7]);
            }
        }

        if (nv) {
            int4 o;
            o.x = (int)f2b(acc[0]) | ((int)f2b(acc[1]) << 16);
            o.y = (int)f2b(acc[2]) | ((int)f2b(acc[3]) << 16);
            o.z = (int)f2b(acc[4]) | ((int)f2b(acc[5]) << 16);
            o.w = (int)f2b(acc[6]) | ((int)f2b(acc[7]) << 16);
            *reinterpret_cast<int4*>(aggOut + ((size_t)node << 6) + l8 * 8) = o;
        }
    }
}

// ---------------------- GEMM: h = relu(agg @ Wr + x @ Ws + b), bf16 via MFMA
__global__ __launch_bounds__(256) void gemm_kernel(
    const unsigned short* __restrict__ agg, const unsigned short* __restrict__ xin,
    const float* __restrict__ Wr, const float* __restrict__ Ws,
    const float* __restrict__ b, unsigned short* __restrict__ out, int n)
{
    __shared__ __align__(16) unsigned short bfrag[2][2][4][64][8];   // 16 KB
    int tid = threadIdx.x;
    for (int i = tid; i < 8192; i += 256) {
        int op = i >> 12;
        int ks = (i >> 11) & 1;
        int ct = (i >> 9) & 3;
        int l  = (i >> 3) & 63;
        int j  = i & 7;
        int k   = ks * 32 + (l >> 4) * 8 + j;
        int col = ct * 16 + (l & 15);
        const float* W = op ? Ws : Wr;
        ((unsigned short*)bfrag)[i] = f2b(W[k * GCN_F + col]);
    }
    __syncthreads();

    int lane = tid & 63, wave = tid >> 6;
    int l15 = lane & 15, lhi = lane >> 4;

    bf16x8 B[2][2][4];
#pragma unroll
    for (int op = 0; op < 2; ++op)
#pragma unroll
        for (int ks = 0; ks < 2; ++ks)
#pragma unroll
            for (int ct = 0; ct < 4; ++ct)
                B[op][ks][ct] = *reinterpret_cast<const bf16x8*>(&bfrag[op][ks][ct][lane][0]);

    float bias[4];
#pragma unroll
    for (int ct = 0; ct < 4; ++ct) bias[ct] = b[ct * 16 + l15];

    int ntiles = (n + 15) >> 4;
    for (int t = blockIdx.x * 4 + wave; t < ntiles; t += gridDim.x * 4) {
        int row = t * 16 + l15;
        int arow = min(row, n - 1);
        const unsigned short* ap = agg + (size_t)arow * GCN_F + lhi * 8;
        const unsigned short* xp = xin + (size_t)arow * GCN_F + lhi * 8;
        bf16x8 a0 = *reinterpret_cast<const bf16x8*>(ap);
        bf16x8 a1 = *reinterpret_cast<const bf16x8*>(ap + 32);
        bf16x8 x0 = *reinterpret_cast<const bf16x8*>(xp);
        bf16x8 x1 = *reinterpret_cast<const bf16x8*>(xp + 32);
#pragma unroll
        for (int ct = 0; ct < 4; ++ct) {
            f32x4 acc = {0.f, 0.f, 0.f, 0.f};
            acc = __builtin_amdgcn_mfma_f32_16x16x32_bf16(a0, B[0][0][ct], acc, 0, 0, 0);
            acc = __builtin_amdgcn_mfma_f32_16x16x32_bf16(a1, B[0][1][ct], acc, 0, 0, 0);
            acc = __builtin_amdgcn_mfma_f32_16x16x32_bf16(x0, B[1][0][ct], acc, 0, 0, 0);
            acc = __builtin_amdgcn_mfma_f32_16x16x32_bf16(x1, B[1][1][ct], acc, 0, 0, 0);
            int col = ct * 16 + l15;
#pragma unroll
            for (int r = 0; r < 4; ++r) {
                int orow = t * 16 + lhi * 4 + r;
                if (orow < n) {
                    float v = fmaxf(acc[r] + bias[ct], 0.f);
                    out[(size_t)orow * GCN_F + col] = f2b(v);
                }
            }
        }
    }
}

// ------------------------------------------------- mean pool + linear head
__global__ __launch_bounds__(256) void pool_kernel(
    const unsigned short* __restrict__ h, const int* __restrict__ batch,
    const float* __restrict__ Wl, const float* __restrict__ bl,
    float* __restrict__ out, int n)
{
    int g    = blockIdx.x;
    int tid  = threadIdx.x;
    int lane = tid & 63;
    int wave = tid >> 6;

    int i0, i1;
    {
        int lo = 0, hi = n;
        while (lo < hi) { int mid = (lo + hi) >> 1; if (batch[mid] < g) lo = mid + 1; else hi = mid; }
        i0 = lo;
        lo = i0; hi = n;
        while (lo < hi) { int mid = (lo + hi) >> 1; if (batch[mid] < g + 1) lo = mid + 1; else hi = mid; }
        i1 = lo;
    }

    float s = 0.f;
    for (int i = i0 + wave; i < i1; i += 4) s += b2f(h[(size_t)i * GCN_F + lane]);

    __shared__ float sp[4][GCN_F];
    sp[wave][lane] = s;
    __syncthreads();
    if (wave == 0) {
        float tot = sp[0][lane] + sp[1][lane] + sp[2][lane] + sp[3][lane];
        float cntf = (float)(i1 - i0);
        sp[0][lane] = tot / fmaxf(cntf, 1.f);
    }
    __syncthreads();
    if (tid < GCN_C) {
        float o = bl[tid];
#pragma unroll
        for (int j = 0; j < GCN_F; ++j) o += sp[0][j] * Wl[j * GCN_C + tid];
        out[g * GCN_C + tid] = o;
    }
}

// --------------------------------------------------------------------------
extern "C" void kernel_launch(void* const* d_in, const int* in_sizes, int n_in,
                              void* d_out, int out_size, void* d_ws, size_t ws_size,
                              hipStream_t stream) {
    const float* x     = (const float*)d_in[0];
    const int*   ei    = (const int*)d_in[1];
    const float* ew    = (const float*)d_in[2];
    const int*   batch = (const int*)d_in[3];
    const float* W1r   = (const float*)d_in[4];
    const float* W1s   = (const float*)d_in[5];
    const float* b1    = (const float*)d_in[6];
    const float* W2r   = (const float*)d_in[7];
    const float* W2s   = (const float*)d_in[8];
    const float* b2    = (const float*)d_in[9];
    const float* W3r   = (const float*)d_in[10];
    const float* W3s   = (const float*)d_in[11];
    const float* b3    = (const float*)d_in[12];
    const float* Wl    = (const float*)d_in[13];
    const float* bl    = (const float*)d_in[14];
    float* out = (float*)d_out;

    const int N = in_sizes[0] / GCN_F;   // 100000
    const int E = in_sizes[2];           // 1000000
    const int G = out_size / GCN_C;      // 256
    const int NCB = (N + CB_NODES - 1) / CB_NODES;  // 196 coarse buckets

    const int* src = ei;
    const int* dst = ei + E;

    // workspace layout (16B aligned)
    char* ws = (char*)d_ws;
    size_t off = 0;
    size_t csz = ((size_t)NCB * 4 + 15) & ~(size_t)15;
    int* bcnt    = (int*)(ws + off);  off += csz;
    int* gcursor = (int*)(ws + off);  off += csz;
    int* gstart  = (int*)(ws + off);  off += ((size_t)(NCB + 1) * 4 + 15) & ~(size_t)15;
    int* offsets = (int*)(ws + off);  off += ((size_t)(N + 1) * 4 + 15) & ~(size_t)15;
    int2* ebufA  = (int2*)(ws + off); off += (size_t)E * 8;
    int2* ebufS  = (int2*)(ws + off); off += (size_t)E * 8;
    unsigned short* buf0 = (unsigned short*)(ws + off); off += (size_t)N * GCN_F * 2;
    unsigned short* buf1 = (unsigned short*)(ws + off); off += (size_t)N * GCN_F * 2;
    unsigned short* aggB = (unsigned short*)(ws + off); off += (size_t)N * GCN_F * 2;

    int hblocks = (E + 4095) / 4096;
    int sblocks = (E + SC_CHUNK - 1) / SC_CHUNK;

    hipMemsetAsync(bcnt, 0, csz * 2, stream);   // bcnt + gcursor
    histC_kernel<<<hblocks, 256, 0, stream>>>(dst, bcnt, E, NCB);
    bscan_kernel<<<1, 64, 0, stream>>>(bcnt, gstart, NCB);
    scatterC_kernel<<<sblocks, 256, 0, stream>>>(src, dst, ew, gstart, gcursor, ebufA, E, NCB);
    sortCB_kernel<<<NCB, 256, 0, stream>>>(ebufA, gstart, ebufS, offsets, N, E);

    cvt_kernel<<<1024, 256, 0, stream>>>(x, buf0, N * GCN_F / 4);

    const int SBLK = 2048, GBLK = 1563;
    // layer 1: buf0 -> buf1
    spmm8_kernel<<<SBLK, 256, 0, stream>>>(buf0, offsets, ebufS, aggB, N);
    gemm_kernel<<<GBLK, 256, 0, stream>>>(aggB, buf0, W1r, W1s, b1, buf1, N);
    // layer 2: buf1 -> buf0
    spmm8_kernel<<<SBLK, 256, 0, stream>>>(buf1, offsets, ebufS, aggB, N);
    gemm_kernel<<<GBLK, 256, 0, stream>>>(aggB, buf1, W2r, W2s, b2, buf0, N);
    // layer 3: buf0 -> buf1
    spmm8_kernel<<<SBLK, 256, 0, stream>>>(buf0, offsets, ebufS, aggB, N);
    gemm_kernel<<<GBLK, 256, 0, stream>>>(aggB, buf0, W3r, W3s, b3, buf1, N);

    pool_kernel<<<G, 256, 0, stream>>>(buf1, batch, Wl, bl, out, N);
}

// Round 9
// 270.855 us; speedup vs baseline: 6.3101x; 1.0030x over previous
//
#include <hip/hip_runtime.h>

// GCNe: 3-layer edge-weighted GCN + mean pool + linear head.
// N=100000, E=1000000, F=H=64, G=256, C=10.
//
// R9 = R8 + replace hipMemsetAsync (rocclr fillBuffer = ~40us in-graph!) with
// a tiny zero_kernel. Pipeline: coarse-bucket hist -> scan -> block-sorted
// scatter (no XCD write amplification) -> per-bucket LDS counting sort (exact
// CSR) -> per layer: spmm8 (wave = 8 nodes x 8 lanes, int4 gathers,
// ds_bpermute broadcast) + MFMA bf16 GEMM. bf16 node features throughout.

#define GCN_F 64
#define GCN_C 10
#define CB_SHIFT 9
#define CB_NODES 512          // nodes per coarse bucket
#define NCB_MAX 200           // >= ceil(N/512)=196
#define CAP 7168              // max edges per coarse bucket (mean 5102)
#define SC_CHUNK 2048         // edges per scatter block

typedef __attribute__((ext_vector_type(8))) short bf16x8;
typedef __attribute__((ext_vector_type(4))) float f32x4;

__device__ __forceinline__ unsigned short f2b(float v) {
    union { float f; unsigned int u; } c; c.f = v;
    unsigned int u = c.u;
    return (unsigned short)((u + 0x7FFFu + ((u >> 16) & 1u)) >> 16);  // RNE
}
__device__ __forceinline__ float b2f(unsigned short u) {
    union { unsigned int u; float f; } c; c.u = ((unsigned int)u) << 16; return c.f;
}

// ------------------------------------------------------------- zero scratch
__global__ __launch_bounds__(256) void zero_kernel(int* __restrict__ p, int n) {
    int i = blockIdx.x * 256 + threadIdx.x;
    if (i < n) p[i] = 0;
}

// --------------------------- coarse-bucket histogram (LDS-staged)
__global__ __launch_bounds__(256) void histC_kernel(const int* __restrict__ dst,
                                                    int* __restrict__ bcnt,
                                                    int E, int NCB) {
    __shared__ int h[NCB_MAX];
    int tid = threadIdx.x;
    for (int i = tid; i < NCB; i += 256) h[i] = 0;
    __syncthreads();
    int e0 = blockIdx.x * 4096 + tid;
#pragma unroll
    for (int k = 0; k < 16; ++k) {
        int e = e0 + k * 256;
        if (e < E) atomicAdd(&h[dst[e] >> CB_SHIFT], 1);
    }
    __syncthreads();
    for (int i = tid; i < NCB; i += 256)
        if (h[i]) atomicAdd(&bcnt[i], h[i]);
}

// ------------------------------------------------ bucket scan (one wave)
__global__ void bscan_kernel(const int* __restrict__ bcnt, int* __restrict__ gstart,
                             int nb) {
    int lane = threadIdx.x;
    int carry = 0;
    for (int base = 0; base < nb; base += 64) {
        int i = base + lane;
        int v = (i < nb) ? bcnt[i] : 0;
        int sc = v;
#pragma unroll
        for (int off = 1; off < 64; off <<= 1) {
            int t = __shfl_up(sc, off);
            if (lane >= off) sc += t;
        }
        if (i < nb) gstart[i] = carry + sc - v;   // exclusive
        carry += __shfl(sc, 63);
    }
    if (lane == 0) gstart[nb] = carry;            // = E
}

// ------------- scatter: block-local counting sort + chunk-reserved run writes
// rec.x = src | (dst&511)<<17 ; rec.y = bits(ew)
__global__ __launch_bounds__(256) void scatterC_kernel(
    const int* __restrict__ src, const int* __restrict__ dst,
    const float* __restrict__ ew, const int* __restrict__ gstart,
    int* __restrict__ gcursor, int2* __restrict__ ebufA, int E, int NCB) {
    __shared__ int2 recS[SC_CHUNK];     // 16 KB
    __shared__ int gdest[SC_CHUNK];     // 8 KB
    __shared__ int hist[NCB_MAX];
    __shared__ int lstart[NCB_MAX];
    __shared__ int gbase[NCB_MAX];
    __shared__ int cur[NCB_MAX];
    __shared__ int sb[256];

    int tid = threadIdx.x;
    int base = blockIdx.x * SC_CHUNK;
    int m = min(SC_CHUNK, E - base);

    for (int i = tid; i < NCB; i += 256) hist[i] = 0;
    __syncthreads();

    int2 rec[8];
    int bk[8];
#pragma unroll
    for (int k = 0; k < 8; ++k) {
        int e = base + k * 256 + tid;
        if (e < E) {
            int d = dst[e];
            bk[k] = d >> CB_SHIFT;
            rec[k] = make_int2(src[e] | ((d & (CB_NODES - 1)) << 17),
                               __float_as_int(ew[e]));
            atomicAdd(&hist[bk[k]], 1);
        } else bk[k] = -1;
    }
    __syncthreads();

    // block-wide exclusive scan of hist[0..NCB)
    int v = (tid < NCB) ? hist[tid] : 0;
    sb[tid] = v;
    __syncthreads();
    for (int o = 1; o < 256; o <<= 1) {
        int t = (tid >= o) ? sb[tid - o] : 0;
        __syncthreads();
        sb[tid] += t;
        __syncthreads();
    }
    if (tid < NCB) {
        int excl = sb[tid] - v;
        lstart[tid] = excl;
        cur[tid] = excl;
        gbase[tid] = (v > 0) ? atomicAdd(&gcursor[tid], v) : 0;  // reserve run
    }
    __syncthreads();

    // place records into LDS sorted by bucket; record global destination
#pragma unroll
    for (int k = 0; k < 8; ++k) {
        if (bk[k] >= 0) {
            int p = atomicAdd(&cur[bk[k]], 1);
            recS[p] = rec[k];
            gdest[p] = gstart[bk[k]] + gbase[bk[k]] + (p - lstart[bk[k]]);
        }
    }
    __syncthreads();

    // coalesced staged write (consecutive i within a run -> consecutive dest)
    for (int i = tid; i < m; i += 256) ebufA[gdest[i]] = recS[i];
}

// -------------- per-bucket LDS counting sort -> sorted edges + node offsets
__global__ __launch_bounds__(256) void sortCB_kernel(
    const int2* __restrict__ ebufA, const int* __restrict__ gstart,
    int2* __restrict__ ebufS, int* __restrict__ offsets, int N, int E) {
    __shared__ int2 rec[CAP];                 // 56 KB
    __shared__ int cnt[CB_NODES];
    __shared__ int cur[CB_NODES];
    __shared__ int sbuf[256];
    int cb = blockIdx.x, tid = threadIdx.x;
    int e0 = gstart[cb], e1 = gstart[cb + 1];
    int m = min(e1 - e0, CAP);

    for (int i = tid; i < m; i += 256) rec[i] = ebufA[e0 + i];
    for (int i = tid; i < CB_NODES; i += 256) cnt[i] = 0;
    __syncthreads();
    for (int i = tid; i < m; i += 256)
        atomicAdd(&cnt[(unsigned)rec[i].x >> 17], 1);
    __syncthreads();

    // exclusive scan over 512 counts (thread owns 2)
    int c0 = cnt[2 * tid], c1 = cnt[2 * tid + 1];
    int part = c0 + c1;
    sbuf[tid] = part;
    __syncthreads();
    for (int off = 1; off < 256; off <<= 1) {
        int t = (tid >= off) ? sbuf[tid - off] : 0;
        __syncthreads();
        sbuf[tid] += t;
        __syncthreads();
    }
    int excl = sbuf[tid] - part;
    int pre0 = excl, pre1 = excl + c0;
    cur[2 * tid] = pre0;
    cur[2 * tid + 1] = pre1;
    int g0 = cb * CB_NODES + 2 * tid;
    if (g0 <= N)     offsets[g0]     = e0 + pre0;
    if (g0 + 1 <= N) offsets[g0 + 1] = e0 + pre1;
    __syncthreads();

    for (int i = tid; i < m; i += 256) {
        int d9 = (unsigned)rec[i].x >> 17;
        int pos = atomicAdd(&cur[d9], 1);
        ebufS[e0 + pos] = make_int2(rec[i].x & 0x1FFFF, rec[i].y);
    }
}

// ----------------------------------------------------- fp32 -> bf16 convert
__global__ __launch_bounds__(256) void cvt_kernel(const float* __restrict__ in,
                                                  unsigned short* __restrict__ out,
                                                  int n4) {
    int stride = gridDim.x * blockDim.x;
    for (int i = blockIdx.x * blockDim.x + threadIdx.x; i < n4; i += stride) {
        float4 v = reinterpret_cast<const float4*>(in)[i];
        ushort4 o;
        o.x = f2b(v.x); o.y = f2b(v.y); o.z = f2b(v.z); o.w = f2b(v.w);
        reinterpret_cast<ushort4*>(out)[i] = o;
    }
}

// --------------------- SpMM: wave = 8 nodes x 8 lanes; lane = 8 features
__global__ __launch_bounds__(256) void spmm8_kernel(
    const unsigned short* __restrict__ xin, const int* __restrict__ offsets,
    const int2* __restrict__ ebufS, unsigned short* __restrict__ aggOut, int n)
{
    int tid = threadIdx.x, lane = tid & 63, wave = tid >> 6;
    int l8 = lane & 7;
    int gbase = (lane & 56) << 2;           // byte addr of group's lane 0
    int nbase0 = (blockIdx.x * 4 + wave) * 8;
    int nstride = gridDim.x * 32;

    for (int nb = nbase0; nb < n; nb += nstride) {
        int node = nb + (lane >> 3);
        bool nv = node < n;
        int p0 = 0, p1 = 0;
        if (nv) { p0 = offsets[node]; p1 = offsets[node + 1]; }
        float acc[8] = {0.f, 0.f, 0.f, 0.f, 0.f, 0.f, 0.f, 0.f};

        for (int c = 0;; ++c) {
            int idx = p0 + c * 8 + l8;
            bool v = idx < p1;
            if (!__any(v)) break;
            int2 er = ebufS[v ? idx : 0];
            int s  = v ? er.x : 0;
            int wb = v ? er.y : 0;

            int sj[8], wj[8];
#pragma unroll
            for (int j = 0; j < 8; ++j) {
                sj[j] = __builtin_amdgcn_ds_bpermute(gbase + (j << 2), s);
                wj[j] = __builtin_amdgcn_ds_bpermute(gbase + (j << 2), wb);
            }
#pragma unroll
            for (int j = 0; j < 8; ++j) {
                float wf = __int_as_float(wj[j]);
                const int4 r = *reinterpret_cast<const int4*>(
                    xin + ((size_t)sj[j] << 6) + l8 * 8);
                acc[0] = fmaf(__int_as_float(r.x << 16),          wf, acc[0]);
                acc[1] = fmaf(__int_as_float(r.x & 0xFFFF0000),   wf, acc[1]);
                acc[2] = fmaf(__int_as_float(r.y << 16),          wf, acc[2]);
                acc[3] = fmaf(__int_as_float(r.y & 0xFFFF0000),   wf, acc[3]);
                acc[4] = fmaf(__int_as_float(r.z << 16),          wf, acc[4]);
                acc[5] = fmaf(__int_as_float(r.z & 0xFFFF0000),   wf, acc[5]);
                acc[6] = fmaf(__int_as_float(r.w << 16),          wf, acc[6]);
                acc[7] = fmaf(__int_as_float(r.w & 0xFFFF0000),   wf, acc[7]);
            }
        }

        if (nv) {
            int4 o;
            o.x = (int)f2b(acc[0]) | ((int)f2b(acc[1]) << 16);
            o.y = (int)f2b(acc[2]) | ((int)f2b(acc[3]) << 16);
            o.z = (int)f2b(acc[4]) | ((int)f2b(acc[5]) << 16);
            o.w = (int)f2b(acc[6]) | ((int)f2b(acc[7]) << 16);
            *reinterpret_cast<int4*>(aggOut + ((size_t)node << 6) + l8 * 8) = o;
        }
    }
}

// ---------------------- GEMM: h = relu(agg @ Wr + x @ Ws + b), bf16 via MFMA
__global__ __launch_bounds__(256) void gemm_kernel(
    const unsigned short* __restrict__ agg, const unsigned short* __restrict__ xin,
    const float* __restrict__ Wr, const float* __restrict__ Ws,
    const float* __restrict__ b, unsigned short* __restrict__ out, int n)
{
    __shared__ __align__(16) unsigned short bfrag[2][2][4][64][8];   // 16 KB
    int tid = threadIdx.x;
    for (int i = tid; i < 8192; i += 256) {
        int op = i >> 12;
        int ks = (i >> 11) & 1;
        int ct = (i >> 9) & 3;
        int l  = (i >> 3) & 63;
        int j  = i & 7;
        int k   = ks * 32 + (l >> 4) * 8 + j;
        int col = ct * 16 + (l & 15);
        const float* W = op ? Ws : Wr;
        ((unsigned short*)bfrag)[i] = f2b(W[k * GCN_F + col]);
    }
    __syncthreads();

    int lane = tid & 63, wave = tid >> 6;
    int l15 = lane & 15, lhi = lane >> 4;

    bf16x8 B[2][2][4];
#pragma unroll
    for (int op = 0; op < 2; ++op)
#pragma unroll
        for (int ks = 0; ks < 2; ++ks)
#pragma unroll
            for (int ct = 0; ct < 4; ++ct)
                B[op][ks][ct] = *reinterpret_cast<const bf16x8*>(&bfrag[op][ks][ct][lane][0]);

    float bias[4];
#pragma unroll
    for (int ct = 0; ct < 4; ++ct) bias[ct] = b[ct * 16 + l15];

    int ntiles = (n + 15) >> 4;
    for (int t = blockIdx.x * 4 + wave; t < ntiles; t += gridDim.x * 4) {
        int row = t * 16 + l15;
        int arow = min(row, n - 1);
        const unsigned short* ap = agg + (size_t)arow * GCN_F + lhi * 8;
        const unsigned short* xp = xin + (size_t)arow * GCN_F + lhi * 8;
        bf16x8 a0 = *reinterpret_cast<const bf16x8*>(ap);
        bf16x8 a1 = *reinterpret_cast<const bf16x8*>(ap + 32);
        bf16x8 x0 = *reinterpret_cast<const bf16x8*>(xp);
        bf16x8 x1 = *reinterpret_cast<const bf16x8*>(xp + 32);
#pragma unroll
        for (int ct = 0; ct < 4; ++ct) {
            f32x4 acc = {0.f, 0.f, 0.f, 0.f};
            acc = __builtin_amdgcn_mfma_f32_16x16x32_bf16(a0, B[0][0][ct], acc, 0, 0, 0);
            acc = __builtin_amdgcn_mfma_f32_16x16x32_bf16(a1, B[0][1][ct], acc, 0, 0, 0);
            acc = __builtin_amdgcn_mfma_f32_16x16x32_bf16(x0, B[1][0][ct], acc, 0, 0, 0);
            acc = __builtin_amdgcn_mfma_f32_16x16x32_bf16(x1, B[1][1][ct], acc, 0, 0, 0);
            int col = ct * 16 + l15;
#pragma unroll
            for (int r = 0; r < 4; ++r) {
                int orow = t * 16 + lhi * 4 + r;
                if (orow < n) {
                    float v = fmaxf(acc[r] + bias[ct], 0.f);
                    out[(size_t)orow * GCN_F + col] = f2b(v);
                }
            }
        }
    }
}

// ------------------------------------------------- mean pool + linear head
__global__ __launch_bounds__(256) void pool_kernel(
    const unsigned short* __restrict__ h, const int* __restrict__ batch,
    const float* __restrict__ Wl, const float* __restrict__ bl,
    float* __restrict__ out, int n)
{
    int g    = blockIdx.x;
    int tid  = threadIdx.x;
    int lane = tid & 63;
    int wave = tid >> 6;

    int i0, i1;
    {
        int lo = 0, hi = n;
        while (lo < hi) { int mid = (lo + hi) >> 1; if (batch[mid] < g) lo = mid + 1; else hi = mid; }
        i0 = lo;
        lo = i0; hi = n;
        while (lo < hi) { int mid = (lo + hi) >> 1; if (batch[mid] < g + 1) lo = mid + 1; else hi = mid; }
        i1 = lo;
    }

    float s = 0.f;
    for (int i = i0 + wave; i < i1; i += 4) s += b2f(h[(size_t)i * GCN_F + lane]);

    __shared__ float sp[4][GCN_F];
    sp[wave][lane] = s;
    __syncthreads();
    if (wave == 0) {
        float tot = sp[0][lane] + sp[1][lane] + sp[2][lane] + sp[3][lane];
        float cntf = (float)(i1 - i0);
        sp[0][lane] = tot / fmaxf(cntf, 1.f);
    }
    __syncthreads();
    if (tid < GCN_C) {
        float o = bl[tid];
#pragma unroll
        for (int j = 0; j < GCN_F; ++j) o += sp[0][j] * Wl[j * GCN_C + tid];
        out[g * GCN_C + tid] = o;
    }
}

// --------------------------------------------------------------------------
extern "C" void kernel_launch(void* const* d_in, const int* in_sizes, int n_in,
                              void* d_out, int out_size, void* d_ws, size_t ws_size,
                              hipStream_t stream) {
    const float* x     = (const float*)d_in[0];
    const int*   ei    = (const int*)d_in[1];
    const float* ew    = (const float*)d_in[2];
    const int*   batch = (const int*)d_in[3];
    const float* W1r   = (const float*)d_in[4];
    const float* W1s   = (const float*)d_in[5];
    const float* b1    = (const float*)d_in[6];
    const float* W2r   = (const float*)d_in[7];
    const float* W2s   = (const float*)d_in[8];
    const float* b2    = (const float*)d_in[9];
    const float* W3r   = (const float*)d_in[10];
    const float* W3s   = (const float*)d_in[11];
    const float* b3    = (const float*)d_in[12];
    const float* Wl    = (const float*)d_in[13];
    const float* bl    = (const float*)d_in[14];
    float* out = (float*)d_out;

    const int N = in_sizes[0] / GCN_F;   // 100000
    const int E = in_sizes[2];           // 1000000
    const int G = out_size / GCN_C;      // 256
    const int NCB = (N + CB_NODES - 1) / CB_NODES;  // 196 coarse buckets

    const int* src = ei;
    const int* dst = ei + E;

    // workspace layout (16B aligned)
    char* ws = (char*)d_ws;
    size_t off = 0;
    size_t csz = ((size_t)NCB * 4 + 15) & ~(size_t)15;
    int* bcnt    = (int*)(ws + off);  off += csz;
    int* gcursor = (int*)(ws + off);  off += csz;
    int* gstart  = (int*)(ws + off);  off += ((size_t)(NCB + 1) * 4 + 15) & ~(size_t)15;
    int* offsets = (int*)(ws + off);  off += ((size_t)(N + 1) * 4 + 15) & ~(size_t)15;
    int2* ebufA  = (int2*)(ws + off); off += (size_t)E * 8;
    int2* ebufS  = (int2*)(ws + off); off += (size_t)E * 8;
    unsigned short* buf0 = (unsigned short*)(ws + off); off += (size_t)N * GCN_F * 2;
    unsigned short* buf1 = (unsigned short*)(ws + off); off += (size_t)N * GCN_F * 2;
    unsigned short* aggB = (unsigned short*)(ws + off); off += (size_t)N * GCN_F * 2;

    int hblocks = (E + 4095) / 4096;
    int sblocks = (E + SC_CHUNK - 1) / SC_CHUNK;
    int zcount  = (int)(csz * 2 / 4);   // bcnt + gcursor (adjacent)

    zero_kernel<<<(zcount + 255) / 256, 256, 0, stream>>>(bcnt, zcount);
    histC_kernel<<<hblocks, 256, 0, stream>>>(dst, bcnt, E, NCB);
    bscan_kernel<<<1, 64, 0, stream>>>(bcnt, gstart, NCB);
    scatterC_kernel<<<sblocks, 256, 0, stream>>>(src, dst, ew, gstart, gcursor, ebufA, E, NCB);
    sortCB_kernel<<<NCB, 256, 0, stream>>>(ebufA, gstart, ebufS, offsets, N, E);

    cvt_kernel<<<1024, 256, 0, stream>>>(x, buf0, N * GCN_F / 4);

    const int SBLK = 2048, GBLK = 1563;
    // layer 1: buf0 -> buf1
    spmm8_kernel<<<SBLK, 256, 0, stream>>>(buf0, offsets, ebufS, aggB, N);
    gemm_kernel<<<GBLK, 256, 0, stream>>>(aggB, buf0, W1r, W1s, b1, buf1, N);
    // layer 2: buf1 -> buf0
    spmm8_kernel<<<SBLK, 256, 0, stream>>>(buf1, offsets, ebufS, aggB, N);
    gemm_kernel<<<GBLK, 256, 0, stream>>>(aggB, buf1, W2r, W2s, b2, buf0, N);
    // layer 3: buf0 -> buf1
    spmm8_kernel<<<SBLK, 256, 0, stream>>>(buf0, offsets, ebufS, aggB, N);
    gemm_kernel<<<GBLK, 256, 0, stream>>>(aggB, buf0, W3r, W3s, b3, buf1, N);

    pool_kernel<<<G, 256, 0, stream>>>(buf1, batch, Wl, bl, out, N);
}

// Round 10
// 262.669 us; speedup vs baseline: 6.5068x; 1.0312x over previous
//
#include <hip/hip_runtime.h>

// GCNe: 3-layer edge-weighted GCN + mean pool + linear head.
// N=100000, E=1000000, F=H=64, G=256, C=10.
//
// R10 = R9 with spmm8 restructured for memory-level parallelism: per chunk,
// all 8 row-gathers batched into r[8] (no intervening VALU -> 8 loads in
// flight), and next chunk's edge-record load issued before processing the
// current chunk (depth-2 pipeline). SBLK=4096 for single balanced pass.
// Pipeline: coarse-bucket hist -> scan -> block-sorted scatter -> per-bucket
// LDS counting sort (exact CSR) -> 3x (spmm8 + MFMA bf16 GEMM) -> pool.

#define GCN_F 64
#define GCN_C 10
#define CB_SHIFT 9
#define CB_NODES 512          // nodes per coarse bucket
#define NCB_MAX 200           // >= ceil(N/512)=196
#define CAP 7168              // max edges per coarse bucket (mean 5102)
#define SC_CHUNK 2048         // edges per scatter block

typedef __attribute__((ext_vector_type(8))) short bf16x8;
typedef __attribute__((ext_vector_type(4))) float f32x4;

__device__ __forceinline__ unsigned short f2b(float v) {
    union { float f; unsigned int u; } c; c.f = v;
    unsigned int u = c.u;
    return (unsigned short)((u + 0x7FFFu + ((u >> 16) & 1u)) >> 16);  // RNE
}
__device__ __forceinline__ float b2f(unsigned short u) {
    union { unsigned int u; float f; } c; c.u = ((unsigned int)u) << 16; return c.f;
}

// ------------------------------------------------------------- zero scratch
__global__ __launch_bounds__(256) void zero_kernel(int* __restrict__ p, int n) {
    int i = blockIdx.x * 256 + threadIdx.x;
    if (i < n) p[i] = 0;
}

// --------------------------- coarse-bucket histogram (LDS-staged)
__global__ __launch_bounds__(256) void histC_kernel(const int* __restrict__ dst,
                                                    int* __restrict__ bcnt,
                                                    int E, int NCB) {
    __shared__ int h[NCB_MAX];
    int tid = threadIdx.x;
    for (int i = tid; i < NCB; i += 256) h[i] = 0;
    __syncthreads();
    int e0 = blockIdx.x * 4096 + tid;
#pragma unroll
    for (int k = 0; k < 16; ++k) {
        int e = e0 + k * 256;
        if (e < E) atomicAdd(&h[dst[e] >> CB_SHIFT], 1);
    }
    __syncthreads();
    for (int i = tid; i < NCB; i += 256)
        if (h[i]) atomicAdd(&bcnt[i], h[i]);
}

// ------------------------------------------------ bucket scan (one wave)
__global__ void bscan_kernel(const int* __restrict__ bcnt, int* __restrict__ gstart,
                             int nb) {
    int lane = threadIdx.x;
    int carry = 0;
    for (int base = 0; base < nb; base += 64) {
        int i = base + lane;
        int v = (i < nb) ? bcnt[i] : 0;
        int sc = v;
#pragma unroll
        for (int off = 1; off < 64; off <<= 1) {
            int t = __shfl_up(sc, off);
            if (lane >= off) sc += t;
        }
        if (i < nb) gstart[i] = carry + sc - v;   // exclusive
        carry += __shfl(sc, 63);
    }
    if (lane == 0) gstart[nb] = carry;            // = E
}

// ------------- scatter: block-local counting sort + chunk-reserved run writes
// rec.x = src | (dst&511)<<17 ; rec.y = bits(ew)
__global__ __launch_bounds__(256) void scatterC_kernel(
    const int* __restrict__ src, const int* __restrict__ dst,
    const float* __restrict__ ew, const int* __restrict__ gstart,
    int* __restrict__ gcursor, int2* __restrict__ ebufA, int E, int NCB) {
    __shared__ int2 recS[SC_CHUNK];     // 16 KB
    __shared__ int gdest[SC_CHUNK];     // 8 KB
    __shared__ int hist[NCB_MAX];
    __shared__ int lstart[NCB_MAX];
    __shared__ int gbase[NCB_MAX];
    __shared__ int cur[NCB_MAX];
    __shared__ int sb[256];

    int tid = threadIdx.x;
    int base = blockIdx.x * SC_CHUNK;
    int m = min(SC_CHUNK, E - base);

    for (int i = tid; i < NCB; i += 256) hist[i] = 0;
    __syncthreads();

    int2 rec[8];
    int bk[8];
#pragma unroll
    for (int k = 0; k < 8; ++k) {
        int e = base + k * 256 + tid;
        if (e < E) {
            int d = dst[e];
            bk[k] = d >> CB_SHIFT;
            rec[k] = make_int2(src[e] | ((d & (CB_NODES - 1)) << 17),
                               __float_as_int(ew[e]));
            atomicAdd(&hist[bk[k]], 1);
        } else bk[k] = -1;
    }
    __syncthreads();

    // block-wide exclusive scan of hist[0..NCB)
    int v = (tid < NCB) ? hist[tid] : 0;
    sb[tid] = v;
    __syncthreads();
    for (int o = 1; o < 256; o <<= 1) {
        int t = (tid >= o) ? sb[tid - o] : 0;
        __syncthreads();
        sb[tid] += t;
        __syncthreads();
    }
    if (tid < NCB) {
        int excl = sb[tid] - v;
        lstart[tid] = excl;
        cur[tid] = excl;
        gbase[tid] = (v > 0) ? atomicAdd(&gcursor[tid], v) : 0;  // reserve run
    }
    __syncthreads();

    // place records into LDS sorted by bucket; record global destination
#pragma unroll
    for (int k = 0; k < 8; ++k) {
        if (bk[k] >= 0) {
            int p = atomicAdd(&cur[bk[k]], 1);
            recS[p] = rec[k];
            gdest[p] = gstart[bk[k]] + gbase[bk[k]] + (p - lstart[bk[k]]);
        }
    }
    __syncthreads();

    // coalesced staged write (consecutive i within a run -> consecutive dest)
    for (int i = tid; i < m; i += 256) ebufA[gdest[i]] = recS[i];
}

// -------------- per-bucket LDS counting sort -> sorted edges + node offsets
__global__ __launch_bounds__(256) void sortCB_kernel(
    const int2* __restrict__ ebufA, const int* __restrict__ gstart,
    int2* __restrict__ ebufS, int* __restrict__ offsets, int N, int E) {
    __shared__ int2 rec[CAP];                 // 56 KB
    __shared__ int cnt[CB_NODES];
    __shared__ int cur[CB_NODES];
    __shared__ int sbuf[256];
    int cb = blockIdx.x, tid = threadIdx.x;
    int e0 = gstart[cb], e1 = gstart[cb + 1];
    int m = min(e1 - e0, CAP);

    for (int i = tid; i < m; i += 256) rec[i] = ebufA[e0 + i];
    for (int i = tid; i < CB_NODES; i += 256) cnt[i] = 0;
    __syncthreads();
    for (int i = tid; i < m; i += 256)
        atomicAdd(&cnt[(unsigned)rec[i].x >> 17], 1);
    __syncthreads();

    // exclusive scan over 512 counts (thread owns 2)
    int c0 = cnt[2 * tid], c1 = cnt[2 * tid + 1];
    int part = c0 + c1;
    sbuf[tid] = part;
    __syncthreads();
    for (int off = 1; off < 256; off <<= 1) {
        int t = (tid >= off) ? sbuf[tid - off] : 0;
        __syncthreads();
        sbuf[tid] += t;
        __syncthreads();
    }
    int excl = sbuf[tid] - part;
    int pre0 = excl, pre1 = excl + c0;
    cur[2 * tid] = pre0;
    cur[2 * tid + 1] = pre1;
    int g0 = cb * CB_NODES + 2 * tid;
    if (g0 <= N)     offsets[g0]     = e0 + pre0;
    if (g0 + 1 <= N) offsets[g0 + 1] = e0 + pre1;
    __syncthreads();

    for (int i = tid; i < m; i += 256) {
        int d9 = (unsigned)rec[i].x >> 17;
        int pos = atomicAdd(&cur[d9], 1);
        ebufS[e0 + pos] = make_int2(rec[i].x & 0x1FFFF, rec[i].y);
    }
}

// ----------------------------------------------------- fp32 -> bf16 convert
__global__ __launch_bounds__(256) void cvt_kernel(const float* __restrict__ in,
                                                  unsigned short* __restrict__ out,
                                                  int n4) {
    int stride = gridDim.x * blockDim.x;
    for (int i = blockIdx.x * blockDim.x + threadIdx.x; i < n4; i += stride) {
        float4 v = reinterpret_cast<const float4*>(in)[i];
        ushort4 o;
        o.x = f2b(v.x); o.y = f2b(v.y); o.z = f2b(v.z); o.w = f2b(v.w);
        reinterpret_cast<ushort4*>(out)[i] = o;
    }
}

// --------------------- SpMM: wave = 8 nodes x 8 lanes; lane = 8 features
// v2: batched gathers (r[8] with no intervening VALU -> 8 loads in flight)
// and next-chunk edge-record load issued before processing current chunk.
__global__ __launch_bounds__(256) void spmm8_kernel(
    const unsigned short* __restrict__ xin, const int* __restrict__ offsets,
    const int2* __restrict__ ebufS, unsigned short* __restrict__ aggOut, int n)
{
    int tid = threadIdx.x, lane = tid & 63, wave = tid >> 6;
    int l8 = lane & 7;
    int gbase = (lane & 56) << 2;           // byte addr of group's lane 0
    int nbase0 = (blockIdx.x * 4 + wave) * 8;
    int nstride = gridDim.x * 32;

    for (int nb = nbase0; nb < n; nb += nstride) {
        int node = nb + (lane >> 3);
        bool nv = node < n;
        int p0 = 0, p1 = 0;
        if (nv) { p0 = offsets[node]; p1 = offsets[node + 1]; }
        float acc[8] = {0.f, 0.f, 0.f, 0.f, 0.f, 0.f, 0.f, 0.f};

        int idx = p0 + l8;
        bool v = idx < p1;
        if (__any(v)) {
            int2 er = ebufS[v ? idx : 0];
            int s  = v ? er.x : 0;
            int wb = v ? er.y : 0;

            for (int c = 1;; ++c) {
                // issue next chunk's edge records early (overlaps processing)
                int idxn = p0 + c * 8 + l8;
                bool vn = idxn < p1;
                int2 ern = ebufS[vn ? idxn : 0];

                // broadcast current chunk's 8 records to the 8-lane group
                int sj[8], wj[8];
#pragma unroll
                for (int j = 0; j < 8; ++j) {
                    sj[j] = __builtin_amdgcn_ds_bpermute(gbase + (j << 2), s);
                    wj[j] = __builtin_amdgcn_ds_bpermute(gbase + (j << 2), wb);
                }
                // batched gathers: 8 independent 16B loads, no VALU between
                int4 r[8];
#pragma unroll
                for (int j = 0; j < 8; ++j)
                    r[j] = *reinterpret_cast<const int4*>(
                        xin + ((size_t)sj[j] << 6) + l8 * 8);
                // unpack + FMA
#pragma unroll
                for (int j = 0; j < 8; ++j) {
                    float wf = __int_as_float(wj[j]);
                    acc[0] = fmaf(__int_as_float(r[j].x << 16),        wf, acc[0]);
                    acc[1] = fmaf(__int_as_float(r[j].x & 0xFFFF0000), wf, acc[1]);
                    acc[2] = fmaf(__int_as_float(r[j].y << 16),        wf, acc[2]);
                    acc[3] = fmaf(__int_as_float(r[j].y & 0xFFFF0000), wf, acc[3]);
                    acc[4] = fmaf(__int_as_float(r[j].z << 16),        wf, acc[4]);
                    acc[5] = fmaf(__int_as_float(r[j].z & 0xFFFF0000), wf, acc[5]);
                    acc[6] = fmaf(__int_as_float(r[j].w << 16),        wf, acc[6]);
                    acc[7] = fmaf(__int_as_float(r[j].w & 0xFFFF0000), wf, acc[7]);
                }

                if (!__any(vn)) break;
                s  = vn ? ern.x : 0;
                wb = vn ? ern.y : 0;
            }
        }

        if (nv) {
            int4 o;
            o.x = (int)f2b(acc[0]) | ((int)f2b(acc[1]) << 16);
            o.y = (int)f2b(acc[2]) | ((int)f2b(acc[3]) << 16);
            o.z = (int)f2b(acc[4]) | ((int)f2b(acc[5]) << 16);
            o.w = (int)f2b(acc[6]) | ((int)f2b(acc[7]) << 16);
            *reinterpret_cast<int4*>(aggOut + ((size_t)node << 6) + l8 * 8) = o;
        }
    }
}

// ---------------------- GEMM: h = relu(agg @ Wr + x @ Ws + b), bf16 via MFMA
__global__ __launch_bounds__(256) void gemm_kernel(
    const unsigned short* __restrict__ agg, const unsigned short* __restrict__ xin,
    const float* __restrict__ Wr, const float* __restrict__ Ws,
    const float* __restrict__ b, unsigned short* __restrict__ out, int n)
{
    __shared__ __align__(16) unsigned short bfrag[2][2][4][64][8];   // 16 KB
    int tid = threadIdx.x;
    for (int i = tid; i < 8192; i += 256) {
        int op = i >> 12;
        int ks = (i >> 11) & 1;
        int ct = (i >> 9) & 3;
        int l  = (i >> 3) & 63;
        int j  = i & 7;
        int k   = ks * 32 + (l >> 4) * 8 + j;
        int col = ct * 16 + (l & 15);
        const float* W = op ? Ws : Wr;
        ((unsigned short*)bfrag)[i] = f2b(W[k * GCN_F + col]);
    }
    __syncthreads();

    int lane = tid & 63, wave = tid >> 6;
    int l15 = lane & 15, lhi = lane >> 4;

    bf16x8 B[2][2][4];
#pragma unroll
    for (int op = 0; op < 2; ++op)
#pragma unroll
        for (int ks = 0; ks < 2; ++ks)
#pragma unroll
            for (int ct = 0; ct < 4; ++ct)
                B[op][ks][ct] = *reinterpret_cast<const bf16x8*>(&bfrag[op][ks][ct][lane][0]);

    float bias[4];
#pragma unroll
    for (int ct = 0; ct < 4; ++ct) bias[ct] = b[ct * 16 + l15];

    int ntiles = (n + 15) >> 4;
    for (int t = blockIdx.x * 4 + wave; t < ntiles; t += gridDim.x * 4) {
        int row = t * 16 + l15;
        int arow = min(row, n - 1);
        const unsigned short* ap = agg + (size_t)arow * GCN_F + lhi * 8;
        const unsigned short* xp = xin + (size_t)arow * GCN_F + lhi * 8;
        bf16x8 a0 = *reinterpret_cast<const bf16x8*>(ap);
        bf16x8 a1 = *reinterpret_cast<const bf16x8*>(ap + 32);
        bf16x8 x0 = *reinterpret_cast<const bf16x8*>(xp);
        bf16x8 x1 = *reinterpret_cast<const bf16x8*>(xp + 32);
#pragma unroll
        for (int ct = 0; ct < 4; ++ct) {
            f32x4 acc = {0.f, 0.f, 0.f, 0.f};
            acc = __builtin_amdgcn_mfma_f32_16x16x32_bf16(a0, B[0][0][ct], acc, 0, 0, 0);
            acc = __builtin_amdgcn_mfma_f32_16x16x32_bf16(a1, B[0][1][ct], acc, 0, 0, 0);
            acc = __builtin_amdgcn_mfma_f32_16x16x32_bf16(x0, B[1][0][ct], acc, 0, 0, 0);
            acc = __builtin_amdgcn_mfma_f32_16x16x32_bf16(x1, B[1][1][ct], acc, 0, 0, 0);
            int col = ct * 16 + l15;
#pragma unroll
            for (int r = 0; r < 4; ++r) {
                int orow = t * 16 + lhi * 4 + r;
                if (orow < n) {
                    float v = fmaxf(acc[r] + bias[ct], 0.f);
                    out[(size_t)orow * GCN_F + col] = f2b(v);
                }
            }
        }
    }
}

// ------------------------------------------------- mean pool + linear head
__global__ __launch_bounds__(256) void pool_kernel(
    const unsigned short* __restrict__ h, const int* __restrict__ batch,
    const float* __restrict__ Wl, const float* __restrict__ bl,
    float* __restrict__ out, int n)
{
    int g    = blockIdx.x;
    int tid  = threadIdx.x;
    int lane = tid & 63;
    int wave = tid >> 6;

    int i0, i1;
    {
        int lo = 0, hi = n;
        while (lo < hi) { int mid = (lo + hi) >> 1; if (batch[mid] < g) lo = mid + 1; else hi = mid; }
        i0 = lo;
        lo = i0; hi = n;
        while (lo < hi) { int mid = (lo + hi) >> 1; if (batch[mid] < g + 1) lo = mid + 1; else hi = mid; }
        i1 = lo;
    }

    float s = 0.f;
    for (int i = i0 + wave; i < i1; i += 4) s += b2f(h[(size_t)i * GCN_F + lane]);

    __shared__ float sp[4][GCN_F];
    sp[wave][lane] = s;
    __syncthreads();
    if (wave == 0) {
        float tot = sp[0][lane] + sp[1][lane] + sp[2][lane] + sp[3][lane];
        float cntf = (float)(i1 - i0);
        sp[0][lane] = tot / fmaxf(cntf, 1.f);
    }
    __syncthreads();
    if (tid < GCN_C) {
        float o = bl[tid];
#pragma unroll
        for (int j = 0; j < GCN_F; ++j) o += sp[0][j] * Wl[j * GCN_C + tid];
        out[g * GCN_C + tid] = o;
    }
}

// --------------------------------------------------------------------------
extern "C" void kernel_launch(void* const* d_in, const int* in_sizes, int n_in,
                              void* d_out, int out_size, void* d_ws, size_t ws_size,
                              hipStream_t stream) {
    const float* x     = (const float*)d_in[0];
    const int*   ei    = (const int*)d_in[1];
    const float* ew    = (const float*)d_in[2];
    const int*   batch = (const int*)d_in[3];
    const float* W1r   = (const float*)d_in[4];
    const float* W1s   = (const float*)d_in[5];
    const float* b1    = (const float*)d_in[6];
    const float* W2r   = (const float*)d_in[7];
    const float* W2s   = (const float*)d_in[8];
    const float* b2    = (const float*)d_in[9];
    const float* W3r   = (const float*)d_in[10];
    const float* W3s   = (const float*)d_in[11];
    const float* b3    = (const float*)d_in[12];
    const float* Wl    = (const float*)d_in[13];
    const float* bl    = (const float*)d_in[14];
    float* out = (float*)d_out;

    const int N = in_sizes[0] / GCN_F;   // 100000
    const int E = in_sizes[2];           // 1000000
    const int G = out_size / GCN_C;      // 256
    const int NCB = (N + CB_NODES - 1) / CB_NODES;  // 196 coarse buckets

    const int* src = ei;
    const int* dst = ei + E;

    // workspace layout (16B aligned)
    char* ws = (char*)d_ws;
    size_t off = 0;
    size_t csz = ((size_t)NCB * 4 + 15) & ~(size_t)15;
    int* bcnt    = (int*)(ws + off);  off += csz;
    int* gcursor = (int*)(ws + off);  off += csz;
    int* gstart  = (int*)(ws + off);  off += ((size_t)(NCB + 1) * 4 + 15) & ~(size_t)15;
    int* offsets = (int*)(ws + off);  off += ((size_t)(N + 1) * 4 + 15) & ~(size_t)15;
    int2* ebufA  = (int2*)(ws + off); off += (size_t)E * 8;
    int2* ebufS  = (int2*)(ws + off); off += (size_t)E * 8;
    unsigned short* buf0 = (unsigned short*)(ws + off); off += (size_t)N * GCN_F * 2;
    unsigned short* buf1 = (unsigned short*)(ws + off); off += (size_t)N * GCN_F * 2;
    unsigned short* aggB = (unsigned short*)(ws + off); off += (size_t)N * GCN_F * 2;

    int hblocks = (E + 4095) / 4096;
    int sblocks = (E + SC_CHUNK - 1) / SC_CHUNK;
    int zcount  = (int)(csz * 2 / 4);   // bcnt + gcursor (adjacent)

    zero_kernel<<<(zcount + 255) / 256, 256, 0, stream>>>(bcnt, zcount);
    histC_kernel<<<hblocks, 256, 0, stream>>>(dst, bcnt, E, NCB);
    bscan_kernel<<<1, 64, 0, stream>>>(bcnt, gstart, NCB);
    scatterC_kernel<<<sblocks, 256, 0, stream>>>(src, dst, ew, gstart, gcursor, ebufA, E, NCB);
    sortCB_kernel<<<NCB, 256, 0, stream>>>(ebufA, gstart, ebufS, offsets, N, E);

    cvt_kernel<<<1024, 256, 0, stream>>>(x, buf0, N * GCN_F / 4);

    const int SBLK = 4096, GBLK = 1563;
    // layer 1: buf0 -> buf1
    spmm8_kernel<<<SBLK, 256, 0, stream>>>(buf0, offsets, ebufS, aggB, N);
    gemm_kernel<<<GBLK, 256, 0, stream>>>(aggB, buf0, W1r, W1s, b1, buf1, N);
    // layer 2: buf1 -> buf0
    spmm8_kernel<<<SBLK, 256, 0, stream>>>(buf1, offsets, ebufS, aggB, N);
    gemm_kernel<<<GBLK, 256, 0, stream>>>(aggB, buf1, W2r, W2s, b2, buf0, N);
    // layer 3: buf0 -> buf1
    spmm8_kernel<<<SBLK, 256, 0, stream>>>(buf0, offsets, ebufS, aggB, N);
    gemm_kernel<<<GBLK, 256, 0, stream>>>(aggB, buf0, W3r, W3s, b3, buf1, N);

    pool_kernel<<<G, 256, 0, stream>>>(buf1, batch, Wl, bl, out, N);
}

// Round 11
// 245.301 us; speedup vs baseline: 6.9675x; 1.0708x over previous
//
#include <hip/hip_runtime.h>

// GCNe: 3-layer edge-weighted GCN + mean pool + linear head.
// N=100000, E=1000000, F=H=64, G=256, C=10.
//
// R11: fuse spmm+gemm per layer (block = 64 contiguous nodes; wave aggregates
// its own 16 nodes -> padded LDS -> wave-local MFMA tile; no agg round-trip,
// no mid-kernel barrier). cvt kernel absorbs scratch zeroing. 9 dispatches.
// Prep: coarse-bucket hist -> scan -> block-sorted scatter -> per-bucket LDS
// counting sort (exact CSR).

#define GCN_F 64
#define GCN_C 10
#define CB_SHIFT 9
#define CB_NODES 512          // nodes per coarse bucket
#define NCB_MAX 200           // >= ceil(N/512)=196
#define CAP 7168              // max edges per coarse bucket (mean 5102)
#define SC_CHUNK 2048         // edges per scatter block

typedef __attribute__((ext_vector_type(8))) short bf16x8;
typedef __attribute__((ext_vector_type(4))) float f32x4;

__device__ __forceinline__ unsigned short f2b(float v) {
    union { float f; unsigned int u; } c; c.f = v;
    unsigned int u = c.u;
    return (unsigned short)((u + 0x7FFFu + ((u >> 16) & 1u)) >> 16);  // RNE
}
__device__ __forceinline__ float b2f(unsigned short u) {
    union { unsigned int u; float f; } c; c.u = ((unsigned int)u) << 16; return c.f;
}

// --------------------- fp32 -> bf16 convert + zero scatter scratch
__global__ __launch_bounds__(256) void cvtz_kernel(const float* __restrict__ in,
                                                   unsigned short* __restrict__ out,
                                                   int n4, int* __restrict__ zp, int zn) {
    int gid = blockIdx.x * 256 + threadIdx.x;
    if (gid < zn) zp[gid] = 0;
    int stride = gridDim.x * 256;
    for (int i = gid; i < n4; i += stride) {
        float4 v = reinterpret_cast<const float4*>(in)[i];
        ushort4 o;
        o.x = f2b(v.x); o.y = f2b(v.y); o.z = f2b(v.z); o.w = f2b(v.w);
        reinterpret_cast<ushort4*>(out)[i] = o;
    }
}

// --------------------------- coarse-bucket histogram (LDS-staged)
__global__ __launch_bounds__(256) void histC_kernel(const int* __restrict__ dst,
                                                    int* __restrict__ bcnt,
                                                    int E, int NCB) {
    __shared__ int h[NCB_MAX];
    int tid = threadIdx.x;
    for (int i = tid; i < NCB; i += 256) h[i] = 0;
    __syncthreads();
    int e0 = blockIdx.x * 4096 + tid;
#pragma unroll
    for (int k = 0; k < 16; ++k) {
        int e = e0 + k * 256;
        if (e < E) atomicAdd(&h[dst[e] >> CB_SHIFT], 1);
    }
    __syncthreads();
    for (int i = tid; i < NCB; i += 256)
        if (h[i]) atomicAdd(&bcnt[i], h[i]);
}

// ------------------------------------------------ bucket scan (one wave)
__global__ void bscan_kernel(const int* __restrict__ bcnt, int* __restrict__ gstart,
                             int nb) {
    int lane = threadIdx.x;
    int carry = 0;
    for (int base = 0; base < nb; base += 64) {
        int i = base + lane;
        int v = (i < nb) ? bcnt[i] : 0;
        int sc = v;
#pragma unroll
        for (int off = 1; off < 64; off <<= 1) {
            int t = __shfl_up(sc, off);
            if (lane >= off) sc += t;
        }
        if (i < nb) gstart[i] = carry + sc - v;   // exclusive
        carry += __shfl(sc, 63);
    }
    if (lane == 0) gstart[nb] = carry;            // = E
}

// ------------- scatter: block-local counting sort + chunk-reserved run writes
// rec.x = src | (dst&511)<<17 ; rec.y = bits(ew)
__global__ __launch_bounds__(256) void scatterC_kernel(
    const int* __restrict__ src, const int* __restrict__ dst,
    const float* __restrict__ ew, const int* __restrict__ gstart,
    int* __restrict__ gcursor, int2* __restrict__ ebufA, int E, int NCB) {
    __shared__ int2 recS[SC_CHUNK];     // 16 KB
    __shared__ int gdest[SC_CHUNK];     // 8 KB
    __shared__ int hist[NCB_MAX];
    __shared__ int lstart[NCB_MAX];
    __shared__ int gbase[NCB_MAX];
    __shared__ int cur[NCB_MAX];
    __shared__ int sb[256];

    int tid = threadIdx.x;
    int base = blockIdx.x * SC_CHUNK;
    int m = min(SC_CHUNK, E - base);

    for (int i = tid; i < NCB; i += 256) hist[i] = 0;
    __syncthreads();

    int2 rec[8];
    int bk[8];
#pragma unroll
    for (int k = 0; k < 8; ++k) {
        int e = base + k * 256 + tid;
        if (e < E) {
            int d = dst[e];
            bk[k] = d >> CB_SHIFT;
            rec[k] = make_int2(src[e] | ((d & (CB_NODES - 1)) << 17),
                               __float_as_int(ew[e]));
            atomicAdd(&hist[bk[k]], 1);
        } else bk[k] = -1;
    }
    __syncthreads();

    // block-wide exclusive scan of hist[0..NCB)
    int v = (tid < NCB) ? hist[tid] : 0;
    sb[tid] = v;
    __syncthreads();
    for (int o = 1; o < 256; o <<= 1) {
        int t = (tid >= o) ? sb[tid - o] : 0;
        __syncthreads();
        sb[tid] += t;
        __syncthreads();
    }
    if (tid < NCB) {
        int excl = sb[tid] - v;
        lstart[tid] = excl;
        cur[tid] = excl;
        gbase[tid] = (v > 0) ? atomicAdd(&gcursor[tid], v) : 0;  // reserve run
    }
    __syncthreads();

    // place records into LDS sorted by bucket; record global destination
#pragma unroll
    for (int k = 0; k < 8; ++k) {
        if (bk[k] >= 0) {
            int p = atomicAdd(&cur[bk[k]], 1);
            recS[p] = rec[k];
            gdest[p] = gstart[bk[k]] + gbase[bk[k]] + (p - lstart[bk[k]]);
        }
    }
    __syncthreads();

    // coalesced staged write (consecutive i within a run -> consecutive dest)
    for (int i = tid; i < m; i += 256) ebufA[gdest[i]] = recS[i];
}

// -------------- per-bucket LDS counting sort -> sorted edges + node offsets
__global__ __launch_bounds__(256) void sortCB_kernel(
    const int2* __restrict__ ebufA, const int* __restrict__ gstart,
    int2* __restrict__ ebufS, int* __restrict__ offsets, int N, int E) {
    __shared__ int2 rec[CAP];                 // 56 KB
    __shared__ int cnt[CB_NODES];
    __shared__ int cur[CB_NODES];
    __shared__ int sbuf[256];
    int cb = blockIdx.x, tid = threadIdx.x;
    int e0 = gstart[cb], e1 = gstart[cb + 1];
    int m = min(e1 - e0, CAP);

    for (int i = tid; i < m; i += 256) rec[i] = ebufA[e0 + i];
    for (int i = tid; i < CB_NODES; i += 256) cnt[i] = 0;
    __syncthreads();
    for (int i = tid; i < m; i += 256)
        atomicAdd(&cnt[(unsigned)rec[i].x >> 17], 1);
    __syncthreads();

    // exclusive scan over 512 counts (thread owns 2)
    int c0 = cnt[2 * tid], c1 = cnt[2 * tid + 1];
    int part = c0 + c1;
    sbuf[tid] = part;
    __syncthreads();
    for (int off = 1; off < 256; off <<= 1) {
        int t = (tid >= off) ? sbuf[tid - off] : 0;
        __syncthreads();
        sbuf[tid] += t;
        __syncthreads();
    }
    int excl = sbuf[tid] - part;
    int pre0 = excl, pre1 = excl + c0;
    cur[2 * tid] = pre0;
    cur[2 * tid + 1] = pre1;
    int g0 = cb * CB_NODES + 2 * tid;
    if (g0 <= N)     offsets[g0]     = e0 + pre0;
    if (g0 + 1 <= N) offsets[g0 + 1] = e0 + pre1;
    __syncthreads();

    for (int i = tid; i < m; i += 256) {
        int d9 = (unsigned)rec[i].x >> 17;
        int pos = atomicAdd(&cur[d9], 1);
        ebufS[e0 + pos] = make_int2(rec[i].x & 0x1FFFF, rec[i].y);
    }
}

// ---------------- fused layer: block = 64 contiguous nodes, 4 waves x 16.
// Wave: spmm (2x 8-node halves, int4 gathers, ds_bpermute broadcast) ->
// padded LDS rows -> wave-local MFMA tile: h = relu(agg@Wr + x@Ws + b).
__global__ __launch_bounds__(256) void layer_kernel(
    const unsigned short* __restrict__ xin, const int* __restrict__ offsets,
    const int2* __restrict__ ebufS, const float* __restrict__ Wr,
    const float* __restrict__ Ws, const float* __restrict__ b,
    unsigned short* __restrict__ out, int n)
{
    __shared__ __align__(16) unsigned short bfrag[2][2][4][64][8];  // 16 KB
    __shared__ __align__(16) unsigned short aggS[4][16][72];        // 9.2 KB (144B rows)
    int tid = threadIdx.x, lane = tid & 63, wave = tid >> 6;

    // build B fragments: [op][ks][ct][lane][j]
    for (int i = tid; i < 8192; i += 256) {
        int op = i >> 12;
        int ks = (i >> 11) & 1;
        int ct = (i >> 9) & 3;
        int l  = (i >> 3) & 63;
        int j  = i & 7;
        int k   = ks * 32 + (l >> 4) * 8 + j;
        int col = ct * 16 + (l & 15);
        const float* W = op ? Ws : Wr;
        ((unsigned short*)bfrag)[i] = f2b(W[k * GCN_F + col]);
    }
    __syncthreads();

    int l8 = lane & 7;
    int grp = lane >> 3;
    int gbase = (lane & 56) << 2;           // byte addr of group's lane 0
    int wbase = blockIdx.x * 64 + wave * 16;

    // ---- spmm phase: this wave's 16 nodes, two 8-node halves
#pragma unroll
    for (int half = 0; half < 2; ++half) {
        int node = wbase + half * 8 + grp;
        bool nv = node < n;
        int p0 = 0, p1 = 0;
        if (nv) { p0 = offsets[node]; p1 = offsets[node + 1]; }
        float acc[8] = {0.f, 0.f, 0.f, 0.f, 0.f, 0.f, 0.f, 0.f};

        int idx = p0 + l8;
        bool v = idx < p1;
        if (__any(v)) {
            int2 er = ebufS[v ? idx : 0];
            int s  = v ? er.x : 0;
            int wb = v ? er.y : 0;

            for (int c = 1;; ++c) {
                int idxn = p0 + c * 8 + l8;
                bool vn = idxn < p1;
                int2 ern = ebufS[vn ? idxn : 0];

                int sj[8], wj[8];
#pragma unroll
                for (int j = 0; j < 8; ++j) {
                    sj[j] = __builtin_amdgcn_ds_bpermute(gbase + (j << 2), s);
                    wj[j] = __builtin_amdgcn_ds_bpermute(gbase + (j << 2), wb);
                }
                int4 r[8];
#pragma unroll
                for (int j = 0; j < 8; ++j)
                    r[j] = *reinterpret_cast<const int4*>(
                        xin + ((size_t)sj[j] << 6) + l8 * 8);
#pragma unroll
                for (int j = 0; j < 8; ++j) {
                    float wf = __int_as_float(wj[j]);
                    acc[0] = fmaf(__int_as_float(r[j].x << 16),        wf, acc[0]);
                    acc[1] = fmaf(__int_as_float(r[j].x & 0xFFFF0000), wf, acc[1]);
                    acc[2] = fmaf(__int_as_float(r[j].y << 16),        wf, acc[2]);
                    acc[3] = fmaf(__int_as_float(r[j].y & 0xFFFF0000), wf, acc[3]);
                    acc[4] = fmaf(__int_as_float(r[j].z << 16),        wf, acc[4]);
                    acc[5] = fmaf(__int_as_float(r[j].z & 0xFFFF0000), wf, acc[5]);
                    acc[6] = fmaf(__int_as_float(r[j].w << 16),        wf, acc[6]);
                    acc[7] = fmaf(__int_as_float(r[j].w & 0xFFFF0000), wf, acc[7]);
                }

                if (!__any(vn)) break;
                s  = vn ? ern.x : 0;
                wb = vn ? ern.y : 0;
            }
        }

        int4 o;
        o.x = (int)f2b(acc[0]) | ((int)f2b(acc[1]) << 16);
        o.y = (int)f2b(acc[2]) | ((int)f2b(acc[3]) << 16);
        o.z = (int)f2b(acc[4]) | ((int)f2b(acc[5]) << 16);
        o.w = (int)f2b(acc[6]) | ((int)f2b(acc[7]) << 16);
        *reinterpret_cast<int4*>(&aggS[wave][half * 8 + grp][l8 * 8]) = o;
    }
    // rows are wave-local: no __syncthreads needed before the GEMM phase.

    // ---- GEMM phase: 16-row MFMA tile for this wave's nodes
    int l15 = lane & 15, lhi = lane >> 4;

    bf16x8 B[2][2][4];
#pragma unroll
    for (int op = 0; op < 2; ++op)
#pragma unroll
        for (int ks = 0; ks < 2; ++ks)
#pragma unroll
            for (int ct = 0; ct < 4; ++ct)
                B[op][ks][ct] = *reinterpret_cast<const bf16x8*>(&bfrag[op][ks][ct][lane][0]);

    float bias[4];
#pragma unroll
    for (int ct = 0; ct < 4; ++ct) bias[ct] = b[ct * 16 + l15];

    bf16x8 a0 = *reinterpret_cast<const bf16x8*>(&aggS[wave][l15][lhi * 8]);
    bf16x8 a1 = *reinterpret_cast<const bf16x8*>(&aggS[wave][l15][32 + lhi * 8]);
    const unsigned short* xp = xin + (size_t)min(wbase + l15, n - 1) * GCN_F + lhi * 8;
    bf16x8 x0 = *reinterpret_cast<const bf16x8*>(xp);
    bf16x8 x1 = *reinterpret_cast<const bf16x8*>(xp + 32);

#pragma unroll
    for (int ct = 0; ct < 4; ++ct) {
        f32x4 acc = {0.f, 0.f, 0.f, 0.f};
        acc = __builtin_amdgcn_mfma_f32_16x16x32_bf16(a0, B[0][0][ct], acc, 0, 0, 0);
        acc = __builtin_amdgcn_mfma_f32_16x16x32_bf16(a1, B[0][1][ct], acc, 0, 0, 0);
        acc = __builtin_amdgcn_mfma_f32_16x16x32_bf16(x0, B[1][0][ct], acc, 0, 0, 0);
        acc = __builtin_amdgcn_mfma_f32_16x16x32_bf16(x1, B[1][1][ct], acc, 0, 0, 0);
        int col = ct * 16 + l15;
#pragma unroll
        for (int r = 0; r < 4; ++r) {
            int orow = wbase + lhi * 4 + r;
            if (orow < n) {
                float v = fmaxf(acc[r] + bias[ct], 0.f);
                out[(size_t)orow * GCN_F + col] = f2b(v);
            }
        }
    }
}

// ------------------------------------------------- mean pool + linear head
__global__ __launch_bounds__(256) void pool_kernel(
    const unsigned short* __restrict__ h, const int* __restrict__ batch,
    const float* __restrict__ Wl, const float* __restrict__ bl,
    float* __restrict__ out, int n)
{
    int g    = blockIdx.x;
    int tid  = threadIdx.x;
    int lane = tid & 63;
    int wave = tid >> 6;

    int i0, i1;
    {
        int lo = 0, hi = n;
        while (lo < hi) { int mid = (lo + hi) >> 1; if (batch[mid] < g) lo = mid + 1; else hi = mid; }
        i0 = lo;
        lo = i0; hi = n;
        while (lo < hi) { int mid = (lo + hi) >> 1; if (batch[mid] < g + 1) lo = mid + 1; else hi = mid; }
        i1 = lo;
    }

    float s = 0.f;
    for (int i = i0 + wave; i < i1; i += 4) s += b2f(h[(size_t)i * GCN_F + lane]);

    __shared__ float sp[4][GCN_F];
    sp[wave][lane] = s;
    __syncthreads();
    if (wave == 0) {
        float tot = sp[0][lane] + sp[1][lane] + sp[2][lane] + sp[3][lane];
        float cntf = (float)(i1 - i0);
        sp[0][lane] = tot / fmaxf(cntf, 1.f);
    }
    __syncthreads();
    if (tid < GCN_C) {
        float o = bl[tid];
#pragma unroll
        for (int j = 0; j < GCN_F; ++j) o += sp[0][j] * Wl[j * GCN_C + tid];
        out[g * GCN_C + tid] = o;
    }
}

// --------------------------------------------------------------------------
extern "C" void kernel_launch(void* const* d_in, const int* in_sizes, int n_in,
                              void* d_out, int out_size, void* d_ws, size_t ws_size,
                              hipStream_t stream) {
    const float* x     = (const float*)d_in[0];
    const int*   ei    = (const int*)d_in[1];
    const float* ew    = (const float*)d_in[2];
    const int*   batch = (const int*)d_in[3];
    const float* W1r   = (const float*)d_in[4];
    const float* W1s   = (const float*)d_in[5];
    const float* b1    = (const float*)d_in[6];
    const float* W2r   = (const float*)d_in[7];
    const float* W2s   = (const float*)d_in[8];
    const float* b2    = (const float*)d_in[9];
    const float* W3r   = (const float*)d_in[10];
    const float* W3s   = (const float*)d_in[11];
    const float* b3    = (const float*)d_in[12];
    const float* Wl    = (const float*)d_in[13];
    const float* bl    = (const float*)d_in[14];
    float* out = (float*)d_out;

    const int N = in_sizes[0] / GCN_F;   // 100000
    const int E = in_sizes[2];           // 1000000
    const int G = out_size / GCN_C;      // 256
    const int NCB = (N + CB_NODES - 1) / CB_NODES;  // 196 coarse buckets

    const int* src = ei;
    const int* dst = ei + E;

    // workspace layout (16B aligned)
    char* ws = (char*)d_ws;
    size_t off = 0;
    size_t csz = ((size_t)NCB * 4 + 15) & ~(size_t)15;
    int* bcnt    = (int*)(ws + off);  off += csz;
    int* gcursor = (int*)(ws + off);  off += csz;
    int* gstart  = (int*)(ws + off);  off += ((size_t)(NCB + 1) * 4 + 15) & ~(size_t)15;
    int* offsets = (int*)(ws + off);  off += ((size_t)(N + 1) * 4 + 15) & ~(size_t)15;
    int2* ebufA  = (int2*)(ws + off); off += (size_t)E * 8;
    int2* ebufS  = (int2*)(ws + off); off += (size_t)E * 8;
    unsigned short* buf0 = (unsigned short*)(ws + off); off += (size_t)N * GCN_F * 2;
    unsigned short* buf1 = (unsigned short*)(ws + off); off += (size_t)N * GCN_F * 2;

    int hblocks = (E + 4095) / 4096;
    int sblocks = (E + SC_CHUNK - 1) / SC_CHUNK;
    int zcount  = (int)(csz * 2 / 4);   // bcnt + gcursor (adjacent)

    cvtz_kernel<<<1024, 256, 0, stream>>>(x, buf0, N * GCN_F / 4, bcnt, zcount);
    histC_kernel<<<hblocks, 256, 0, stream>>>(dst, bcnt, E, NCB);
    bscan_kernel<<<1, 64, 0, stream>>>(bcnt, gstart, NCB);
    scatterC_kernel<<<sblocks, 256, 0, stream>>>(src, dst, ew, gstart, gcursor, ebufA, E, NCB);
    sortCB_kernel<<<NCB, 256, 0, stream>>>(ebufA, gstart, ebufS, offsets, N, E);

    const int LBLK = (N + 63) / 64;   // 1563
    // layer 1: buf0 -> buf1 ; layer 2: buf1 -> buf0 ; layer 3: buf0 -> buf1
    layer_kernel<<<LBLK, 256, 0, stream>>>(buf0, offsets, ebufS, W1r, W1s, b1, buf1, N);
    layer_kernel<<<LBLK, 256, 0, stream>>>(buf1, offsets, ebufS, W2r, W2s, b2, buf0, N);
    layer_kernel<<<LBLK, 256, 0, stream>>>(buf0, offsets, ebufS, W3r, W3s, b3, buf1, N);

    pool_kernel<<<G, 256, 0, stream>>>(buf1, batch, Wl, bl, out, N);
}